// Round 1
// baseline (1794.125 us; speedup 1.0000x reference)
//
#include <hip/hip_runtime.h>
#include <math.h>

#define LL 256
#define CSD 384
#define CZD 128
#define HNUM 8
#define DHS 48
#define DHZ 16

// ---------------- LayerNorm: one block per row, blockDim.x == W ----------------
__global__ void ln_kernel(const float* __restrict__ x, const float* __restrict__ g,
                          const float* __restrict__ b, float* __restrict__ y, int W) {
    size_t row = blockIdx.x;
    int t = threadIdx.x;
    float v = x[row * (size_t)W + t];
    float s = v, s2 = v * v;
#pragma unroll
    for (int o = 32; o > 0; o >>= 1) { s += __shfl_down(s, o); s2 += __shfl_down(s2, o); }
    __shared__ float sh[8], sh2[8];
    int w = t >> 6, nw = W >> 6;
    if ((t & 63) == 0) { sh[w] = s; sh2[w] = s2; }
    __syncthreads();
    if (t == 0) {
        float a = 0, a2 = 0;
        for (int i = 0; i < nw; i++) { a += sh[i]; a2 += sh2[i]; }
        sh[0] = a; sh2[0] = a2;
    }
    __syncthreads();
    float mean = sh[0] / W;
    float var = sh2[0] / W - mean * mean;
    y[row * (size_t)W + t] = (v - mean) * rsqrtf(var + 1e-5f) * g[t] + b[t];
}

// ---------------- pair bias: per pair LN(z)*wzb -> bias[h][i][j] ----------------
__global__ void zbias_kernel(const float* __restrict__ z, const float* __restrict__ g,
                             const float* __restrict__ b, const float* __restrict__ wzb,
                             const float* __restrict__ bzb, float* __restrict__ bias) {
    int p = blockIdx.x;      // i*256+j
    int t = threadIdx.x;     // 0..127
    float v = z[(size_t)p * CZD + t];
    float s = v, s2 = v * v;
#pragma unroll
    for (int o = 32; o > 0; o >>= 1) { s += __shfl_down(s, o); s2 += __shfl_down(s2, o); }
    __shared__ float sh[2], sh2[2];
    __shared__ float zn[CZD];
    if ((t & 63) == 0) { sh[t >> 6] = s; sh2[t >> 6] = s2; }
    __syncthreads();
    float mean = (sh[0] + sh[1]) / 128.f;
    float var = (sh2[0] + sh2[1]) / 128.f - mean * mean;
    zn[t] = (v - mean) * rsqrtf(var + 1e-5f) * g[t] + b[t];
    __syncthreads();
    if (t < HNUM) {
        float acc = bzb[t];
        for (int c = 0; c < CZD; c++) acc += zn[c] * wzb[c * HNUM + t];
        bias[(size_t)t * 65536 + p] = acc;
    }
}

// ---------------- s-track attention: one block per (query l, head h) ----------------
__global__ void sattn_kernel(const float* __restrict__ q, const float* __restrict__ k,
                             const float* __restrict__ v, const float* __restrict__ bias,
                             float* __restrict__ o) {
    int l = blockIdx.x, h = blockIdx.y;
    int m = threadIdx.x;  // 256 keys
    const float* qr = q + (size_t)l * CSD + h * DHS;
    const float* kr = k + (size_t)m * CSD + h * DHS;
    float acc = 0.f;
#pragma unroll
    for (int d = 0; d < DHS; d++) acc += qr[d] * kr[d];
    acc = acc * 0.14433756729740643f + bias[(size_t)h * 65536 + l * 256 + m];

    __shared__ float attn[256];
    __shared__ float redm[4], reds[4];
    float x = acc;
#pragma unroll
    for (int off = 32; off > 0; off >>= 1) x = fmaxf(x, __shfl_down(x, off));
    if ((m & 63) == 0) redm[m >> 6] = x;
    __syncthreads();
    float mx = fmaxf(fmaxf(redm[0], redm[1]), fmaxf(redm[2], redm[3]));
    float p = __expf(acc - mx);
    float ss = p;
#pragma unroll
    for (int off = 32; off > 0; off >>= 1) ss += __shfl_down(ss, off);
    if ((m & 63) == 0) reds[m >> 6] = ss;
    __syncthreads();
    float sum = reds[0] + reds[1] + reds[2] + reds[3];
    attn[m] = p / sum;
    __syncthreads();
    if (m < DHS) {
        float a = 0.f;
        for (int j = 0; j < 256; j++) a += attn[j] * v[(size_t)j * CSD + h * DHS + m];
        o[(size_t)l * CSD + h * DHS + m] = a;
    }
}

// ---------------- pair attention: one block per (seq n, head h); 1 query/thread ----------------
__global__ void pattn_kernel(const float* __restrict__ qkv, float* __restrict__ o) {
    int n = blockIdx.x, h = blockIdx.y;
    int t = threadIdx.x;  // query index l = t, also loads token t's K/V
    __shared__ float ks[256][DHZ];
    __shared__ float vs[256][DHZ];
    const float* base = qkv + ((size_t)n * 256 + t) * (3 * CZD);
#pragma unroll
    for (int d = 0; d < DHZ; d++) {
        ks[t][d] = base[CZD + h * DHZ + d];
        vs[t][d] = base[2 * CZD + h * DHZ + d];
    }
    float qreg[DHZ];
#pragma unroll
    for (int d = 0; d < DHZ; d++) qreg[d] = base[h * DHZ + d];
    __syncthreads();
    // pass 1: max
    float mx = -1e30f;
    for (int m = 0; m < 256; m++) {
        float a = 0.f;
#pragma unroll
        for (int d = 0; d < DHZ; d++) a += qreg[d] * ks[m][d];
        mx = fmaxf(mx, a * 0.25f);
    }
    // pass 2: sum + AV
    float sum = 0.f;
    float oacc[DHZ];
#pragma unroll
    for (int d = 0; d < DHZ; d++) oacc[d] = 0.f;
    for (int m = 0; m < 256; m++) {
        float a = 0.f;
#pragma unroll
        for (int d = 0; d < DHZ; d++) a += qreg[d] * ks[m][d];
        float p = __expf(a * 0.25f - mx);
        sum += p;
#pragma unroll
        for (int d = 0; d < DHZ; d++) oacc[d] += p * vs[m][d];
    }
    float inv = 1.f / sum;
    float* orow = o + ((size_t)n * 256 + t) * CZD + h * DHZ;
#pragma unroll
    for (int d = 0; d < DHZ; d++) orow[d] = oacc[d] * inv;
}

// ---------------- generic tiled GEMM ----------------
// C[m,n] = epi( sum_k A[rowA(m),k] * B(k,n) + bias[n] )
// BT: B is (N,K) row-major (x @ W.T).  APERM: rowA(m) = ((m&255)<<8)|(m>>8), M==65536.
// RES: 0 none, 1 += C (in place), 2 += R.  ACT: 1 = exact GELU (before residual; never both).
template <int BT, int APERM, int RES, int ACT>
__global__ __launch_bounds__(256) void gemm_kernel(const float* __restrict__ A,
                                                   const float* __restrict__ B,
                                                   const float* __restrict__ bias,
                                                   const float* __restrict__ R,
                                                   float* __restrict__ C,
                                                   int M, int N, int K) {
    __shared__ float As[64][17];
    __shared__ float Bs[16][65];
    int tid = threadIdx.x;
    int bm = blockIdx.y * 64, bn = blockIdx.x * 64;
    int tx = tid & 15, ty = tid >> 4;
    float acc[4][4] = {};

    int arow = bm + (tid >> 2);
    size_t aoff;
    if (APERM) aoff = (size_t)(((arow & 255) << 8) | (arow >> 8)) * K;
    else       aoff = (size_t)arow * K;
    int ak = (tid & 3) * 4;

    for (int k0 = 0; k0 < K; k0 += 16) {
        float4 av = *(const float4*)(A + aoff + k0 + ak);
        As[tid >> 2][ak + 0] = av.x;
        As[tid >> 2][ak + 1] = av.y;
        As[tid >> 2][ak + 2] = av.z;
        As[tid >> 2][ak + 3] = av.w;
        if (BT) {
            int bn_l = tid >> 2;  // 0..63
            int bk = (tid & 3) * 4;
            float4 bv = *(const float4*)(B + (size_t)(bn + bn_l) * K + k0 + bk);
            Bs[bk + 0][bn_l] = bv.x;
            Bs[bk + 1][bn_l] = bv.y;
            Bs[bk + 2][bn_l] = bv.z;
            Bs[bk + 3][bn_l] = bv.w;
        } else {
            int bk = tid >> 4;           // 0..15
            int bn_l = (tid & 15) * 4;   // 0..60
            float4 bv = *(const float4*)(B + (size_t)(k0 + bk) * N + bn + bn_l);
            Bs[bk][bn_l + 0] = bv.x;
            Bs[bk][bn_l + 1] = bv.y;
            Bs[bk][bn_l + 2] = bv.z;
            Bs[bk][bn_l + 3] = bv.w;
        }
        __syncthreads();
#pragma unroll
        for (int kk = 0; kk < 16; kk++) {
            float a[4], b[4];
#pragma unroll
            for (int i = 0; i < 4; i++) a[i] = As[ty * 4 + i][kk];
#pragma unroll
            for (int j = 0; j < 4; j++) b[j] = Bs[kk][tx * 4 + j];
#pragma unroll
            for (int i = 0; i < 4; i++)
#pragma unroll
                for (int j = 0; j < 4; j++) acc[i][j] += a[i] * b[j];
        }
        __syncthreads();
    }
#pragma unroll
    for (int i = 0; i < 4; i++) {
        int m = bm + ty * 4 + i;
        size_t crow = (size_t)m * N;
#pragma unroll
        for (int j = 0; j < 4; j++) {
            int n = bn + tx * 4 + j;
            float val = acc[i][j];
            if (bias) val += bias[n];
            if (ACT == 1) val = 0.5f * val * (1.f + erff(val * 0.70710678118654752f));
            if (RES == 1) val += C[crow + n];
            else if (RES == 2) val += R[crow + n];
            C[crow + n] = val;
        }
    }
}

// ---------------- outer-sum: z[i,j,:] += a[i,:] + b[j,:] (float4 over 8.4M) ----------------
__global__ void outer_add_kernel(float* __restrict__ z, const float* __restrict__ a,
                                 const float* __restrict__ b) {
    size_t idx = (size_t)blockIdx.x * blockDim.x + threadIdx.x;  // 2,097,152 float4s
    size_t e = idx * 4;
    int c4 = (int)(e & 127);
    int pair = (int)(e >> 7);
    int i = pair >> 8, j = pair & 255;
    float4 zv = *(float4*)(z + e);
    float4 avv = *(const float4*)(a + (size_t)i * 128 + c4);
    float4 bvv = *(const float4*)(b + (size_t)j * 128 + c4);
    zv.x += avv.x + bvv.x;
    zv.y += avv.y + bvv.y;
    zv.z += avv.z + bvv.z;
    zv.w += avv.w + bvv.w;
    *(float4*)(z + e) = zv;
}

extern "C" void kernel_launch(void* const* d_in, const int* in_sizes, int n_in,
                              void* d_out, int out_size, void* d_ws, size_t ws_size,
                              hipStream_t stream) {
    const float* s_in = (const float*)d_in[0];
    const float* z_in = (const float*)d_in[1];
    const float* sng = (const float*)d_in[3];
    const float* snb = (const float*)d_in[4];
    const float* zng = (const float*)d_in[5];
    const float* znb = (const float*)d_in[6];
    const float* wq = (const float*)d_in[7];
    const float* bq = (const float*)d_in[8];
    const float* wk = (const float*)d_in[9];
    const float* bk = (const float*)d_in[10];
    const float* wv = (const float*)d_in[11];
    const float* bv = (const float*)d_in[12];
    const float* wzb = (const float*)d_in[13];
    const float* bzb = (const float*)d_in[14];
    const float* wo = (const float*)d_in[15];
    const float* bo = (const float*)d_in[16];
    const float* sffw1 = (const float*)d_in[17];
    const float* sffb1 = (const float*)d_in[18];
    const float* sffw2 = (const float*)d_in[19];
    const float* sffb2 = (const float*)d_in[20];
    const float* pzg = (const float*)d_in[21];
    const float* pzb = (const float*)d_in[22];
    const float* rinw = (const float*)d_in[23];
    const float* rinb = (const float*)d_in[24];
    const float* routw = (const float*)d_in[25];
    const float* routb = (const float*)d_in[26];
    const float* cinw = (const float*)d_in[27];
    const float* cinb = (const float*)d_in[28];
    const float* coutw = (const float*)d_in[29];
    const float* coutb = (const float*)d_in[30];
    const float* sziw = (const float*)d_in[31];
    const float* szjw = (const float*)d_in[32];
    const float* zffw1 = (const float*)d_in[33];
    const float* zffb1 = (const float*)d_in[34];
    const float* zffw2 = (const float*)d_in[35];
    const float* zffb2 = (const float*)d_in[36];

    float* ws = (float*)d_ws;
    // big buffers
    float* qkv = ws;                         // 65536*384 = 25,165,824
    float* obuf = ws + 25165824;             // 65536*128 =  8,388,608
    float* hbig = ws;                        // 65536*512 spans qkv+obuf exactly
    float* znp = ws + 33554432;              // 8,388,608
    // small buffers
    float* sn   = ws + 41943040;             // 98,304
    float* qs   = ws + 42041344;
    float* ks_  = ws + 42139648;
    float* vs_  = ws + 42237952;
    float* biasb= ws + 42336256;             // 8*65536
    float* os_  = ws + 42860544;             // 98,304
    float* s1   = ws + 42958848;
    float* sn2  = ws + 43057152;
    float* hs   = ws + 43155456;             // 256*1536
    float* sn3  = ws + 43548672;
    float* aout = ws + 43646976;             // 256*128
    float* bout = ws + 43679744;

    float* sout = (float*)d_out;             // 98,304
    float* zout = sout + 98304;              // 8,388,608

    dim3 b256(256);

    // --- s attention ---
    ln_kernel<<<dim3(LL), dim3(CSD), 0, stream>>>(s_in, sng, snb, sn, CSD);
    zbias_kernel<<<dim3(65536), dim3(CZD), 0, stream>>>(z_in, zng, znb, wzb, bzb, biasb);
    gemm_kernel<0,0,0,0><<<dim3(6,4), b256, 0, stream>>>(sn, wq, bq, nullptr, qs, 256, CSD, CSD);
    gemm_kernel<0,0,0,0><<<dim3(6,4), b256, 0, stream>>>(sn, wk, bk, nullptr, ks_, 256, CSD, CSD);
    gemm_kernel<0,0,0,0><<<dim3(6,4), b256, 0, stream>>>(sn, wv, bv, nullptr, vs_, 256, CSD, CSD);
    sattn_kernel<<<dim3(LL, HNUM), b256, 0, stream>>>(qs, ks_, vs_, biasb, os_);
    gemm_kernel<0,0,2,0><<<dim3(6,4), b256, 0, stream>>>(os_, wo, bo, s_in, s1, 256, CSD, CSD);
    // --- s feedforward ---
    ln_kernel<<<dim3(LL), dim3(CSD), 0, stream>>>(s1, sng, snb, sn2, CSD);
    gemm_kernel<0,0,0,1><<<dim3(24,4), b256, 0, stream>>>(sn2, sffw1, sffb1, nullptr, hs, 256, 1536, CSD);
    gemm_kernel<0,0,2,0><<<dim3(6,4), b256, 0, stream>>>(hs, sffw2, sffb2, s1, sout, 256, CSD, 1536);
    // --- pair LN ---
    ln_kernel<<<dim3(65536), dim3(CZD), 0, stream>>>(z_in, pzg, pzb, znp, CZD);
    // --- row attention ---
    gemm_kernel<1,0,0,0><<<dim3(6,1024), b256, 0, stream>>>(znp, rinw, rinb, nullptr, qkv, 65536, 384, CZD);
    pattn_kernel<<<dim3(256, HNUM), b256, 0, stream>>>(qkv, obuf);
    gemm_kernel<1,0,2,0><<<dim3(2,1024), b256, 0, stream>>>(obuf, routw, routb, z_in, zout, 65536, CZD, CZD);
    // --- col attention ---
    gemm_kernel<1,1,0,0><<<dim3(6,1024), b256, 0, stream>>>(znp, cinw, cinb, nullptr, qkv, 65536, 384, CZD);
    pattn_kernel<<<dim3(256, HNUM), b256, 0, stream>>>(qkv, obuf);
    gemm_kernel<1,1,1,0><<<dim3(2,1024), b256, 0, stream>>>(obuf, coutw, coutb, nullptr, zout, 65536, CZD, CZD);
    // --- outer sum ---
    ln_kernel<<<dim3(LL), dim3(CSD), 0, stream>>>(sout, sng, snb, sn3, CSD);
    gemm_kernel<0,0,0,0><<<dim3(2,4), b256, 0, stream>>>(sn3, sziw, nullptr, nullptr, aout, 256, CZD, CSD);
    gemm_kernel<0,0,0,0><<<dim3(2,4), b256, 0, stream>>>(sn3, szjw, nullptr, nullptr, bout, 256, CZD, CSD);
    outer_add_kernel<<<dim3(8192), b256, 0, stream>>>(zout, aout, bout);
    // --- z feedforward ---
    ln_kernel<<<dim3(65536), dim3(CZD), 0, stream>>>(zout, zng, znb, znp, CZD);
    gemm_kernel<0,0,0,1><<<dim3(8,1024), b256, 0, stream>>>(znp, zffw1, zffb1, nullptr, hbig, 65536, 512, CZD);
    gemm_kernel<0,0,1,0><<<dim3(2,1024), b256, 0, stream>>>(hbig, zffw2, zffb2, nullptr, zout, 65536, CZD, 512);
}

// Round 2
// 1175.641 us; speedup vs baseline: 1.5261x; 1.5261x over previous
//
#include <hip/hip_runtime.h>
#include <math.h>

#define LL 256
#define CSD 384
#define CZD 128
#define HNUM 8
#define DHS 48
#define DHZ 16

typedef __bf16 bf16_t;
typedef bf16_t bf16x8 __attribute__((ext_vector_type(8)));
typedef float f32x4 __attribute__((ext_vector_type(4)));

// ---------------- LayerNorm: one block per row, blockDim.x == W ----------------
template <typename OUT>
__global__ void ln_kernel(const float* __restrict__ x, const float* __restrict__ g,
                          const float* __restrict__ b, OUT* __restrict__ y, int W) {
    size_t row = blockIdx.x;
    int t = threadIdx.x;
    float v = x[row * (size_t)W + t];
    float s = v, s2 = v * v;
#pragma unroll
    for (int o = 32; o > 0; o >>= 1) { s += __shfl_down(s, o); s2 += __shfl_down(s2, o); }
    __shared__ float sh[8], sh2[8];
    int w = t >> 6, nw = W >> 6;
    if ((t & 63) == 0) { sh[w] = s; sh2[w] = s2; }
    __syncthreads();
    if (t == 0) {
        float a = 0, a2 = 0;
        for (int i = 0; i < nw; i++) { a += sh[i]; a2 += sh2[i]; }
        sh[0] = a; sh2[0] = a2;
    }
    __syncthreads();
    float mean = sh[0] / W;
    float var = sh2[0] / W - mean * mean;
    y[row * (size_t)W + t] = (OUT)((v - mean) * rsqrtf(var + 1e-5f) * g[t] + b[t]);
}

// ---------------- pair bias: per pair LN(z)*wzb -> bias[h][i][j] ----------------
__global__ void zbias_kernel(const float* __restrict__ z, const float* __restrict__ g,
                             const float* __restrict__ b, const float* __restrict__ wzb,
                             const float* __restrict__ bzb, float* __restrict__ bias) {
    int p = blockIdx.x;      // i*256+j
    int t = threadIdx.x;     // 0..127
    float v = z[(size_t)p * CZD + t];
    float s = v, s2 = v * v;
#pragma unroll
    for (int o = 32; o > 0; o >>= 1) { s += __shfl_down(s, o); s2 += __shfl_down(s2, o); }
    __shared__ float sh[2], sh2[2];
    __shared__ float zn[CZD];
    if ((t & 63) == 0) { sh[t >> 6] = s; sh2[t >> 6] = s2; }
    __syncthreads();
    float mean = (sh[0] + sh[1]) / 128.f;
    float var = (sh2[0] + sh2[1]) / 128.f - mean * mean;
    zn[t] = (v - mean) * rsqrtf(var + 1e-5f) * g[t] + b[t];
    __syncthreads();
    if (t < HNUM) {
        float acc = bzb[t];
        for (int c = 0; c < CZD; c++) acc += zn[c] * wzb[c * HNUM + t];
        bias[(size_t)t * 65536 + p] = acc;
    }
}

// ---------------- s-track attention: one block per (query l, head h) ----------------
__global__ void sattn_kernel(const float* __restrict__ q, const float* __restrict__ k,
                             const float* __restrict__ v, const float* __restrict__ bias,
                             float* __restrict__ o) {
    int l = blockIdx.x, h = blockIdx.y;
    int m = threadIdx.x;  // 256 keys
    const float* qr = q + (size_t)l * CSD + h * DHS;
    const float* kr = k + (size_t)m * CSD + h * DHS;
    float acc = 0.f;
#pragma unroll
    for (int d = 0; d < DHS; d++) acc += qr[d] * kr[d];
    acc = acc * 0.14433756729740643f + bias[(size_t)h * 65536 + l * 256 + m];

    __shared__ float attn[256];
    __shared__ float redm[4], reds[4];
    float x = acc;
#pragma unroll
    for (int off = 32; off > 0; off >>= 1) x = fmaxf(x, __shfl_down(x, off));
    if ((m & 63) == 0) redm[m >> 6] = x;
    __syncthreads();
    float mx = fmaxf(fmaxf(redm[0], redm[1]), fmaxf(redm[2], redm[3]));
    float p = __expf(acc - mx);
    float ss = p;
#pragma unroll
    for (int off = 32; off > 0; off >>= 1) ss += __shfl_down(ss, off);
    if ((m & 63) == 0) reds[m >> 6] = ss;
    __syncthreads();
    float sum = reds[0] + reds[1] + reds[2] + reds[3];
    attn[m] = p / sum;
    __syncthreads();
    if (m < DHS) {
        float a = 0.f;
        for (int j = 0; j < 256; j++) a += attn[j] * v[(size_t)j * CSD + h * DHS + m];
        o[(size_t)l * CSD + h * DHS + m] = a;
    }
}

// ---------------- pair attention: single-pass softmax (|logit| ~ 2, exp safe) ----------------
// one block per (seq n, head h); 1 query/thread; output bf16
__global__ void pattn_kernel(const float* __restrict__ qkv, bf16_t* __restrict__ o) {
    int n = blockIdx.x, h = blockIdx.y;
    int t = threadIdx.x;
    __shared__ float ks[256][DHZ];
    __shared__ float vs[256][DHZ];
    const float* base = qkv + ((size_t)n * 256 + t) * (3 * CZD);
    float qreg[DHZ];
#pragma unroll
    for (int d = 0; d < DHZ; d++) {
        ks[t][d] = base[CZD + h * DHZ + d];
        vs[t][d] = base[2 * CZD + h * DHZ + d];
        qreg[d] = base[h * DHZ + d] * 0.25f;
    }
    __syncthreads();
    float sum = 0.f;
    float oacc[DHZ];
#pragma unroll
    for (int d = 0; d < DHZ; d++) oacc[d] = 0.f;
    for (int m = 0; m < 256; m++) {
        float a = 0.f;
#pragma unroll
        for (int d = 0; d < DHZ; d++) a += qreg[d] * ks[m][d];
        float p = __expf(a);
        sum += p;
#pragma unroll
        for (int d = 0; d < DHZ; d++) oacc[d] += p * vs[m][d];
    }
    float inv = 1.f / sum;
    bf16_t* orow = o + ((size_t)n * 256 + t) * CZD + h * DHZ;
#pragma unroll
    for (int d = 0; d < DHZ; d++) orow[d] = (bf16_t)(oacc[d] * inv);
}

// ---------------- fp32 tiled GEMM (small s-track mats only) ----------------
template <int RES, int ACT>
__global__ __launch_bounds__(256) void gemm_kernel(const float* __restrict__ A,
                                                   const float* __restrict__ B,
                                                   const float* __restrict__ bias,
                                                   const float* __restrict__ R,
                                                   float* __restrict__ C,
                                                   int M, int N, int K) {
    __shared__ float As[64][17];
    __shared__ float Bs[16][65];
    int tid = threadIdx.x;
    int bm = blockIdx.y * 64, bn = blockIdx.x * 64;
    int tx = tid & 15, ty = tid >> 4;
    float acc[4][4] = {};
    int arow = bm + (tid >> 2);
    size_t aoff = (size_t)arow * K;
    int ak = (tid & 3) * 4;
    for (int k0 = 0; k0 < K; k0 += 16) {
        float4 av = *(const float4*)(A + aoff + k0 + ak);
        As[tid >> 2][ak + 0] = av.x;
        As[tid >> 2][ak + 1] = av.y;
        As[tid >> 2][ak + 2] = av.z;
        As[tid >> 2][ak + 3] = av.w;
        int bk = tid >> 4;
        int bn_l = (tid & 15) * 4;
        float4 bv = *(const float4*)(B + (size_t)(k0 + bk) * N + bn + bn_l);
        Bs[bk][bn_l + 0] = bv.x;
        Bs[bk][bn_l + 1] = bv.y;
        Bs[bk][bn_l + 2] = bv.z;
        Bs[bk][bn_l + 3] = bv.w;
        __syncthreads();
#pragma unroll
        for (int kk = 0; kk < 16; kk++) {
            float a[4], b[4];
#pragma unroll
            for (int i = 0; i < 4; i++) a[i] = As[ty * 4 + i][kk];
#pragma unroll
            for (int j = 0; j < 4; j++) b[j] = Bs[kk][tx * 4 + j];
#pragma unroll
            for (int i = 0; i < 4; i++)
#pragma unroll
                for (int j = 0; j < 4; j++) acc[i][j] += a[i] * b[j];
        }
        __syncthreads();
    }
#pragma unroll
    for (int i = 0; i < 4; i++) {
        int m = bm + ty * 4 + i;
        size_t crow = (size_t)m * N;
#pragma unroll
        for (int j = 0; j < 4; j++) {
            int n = bn + tx * 4 + j;
            float val = acc[i][j];
            if (bias) val += bias[n];
            if (ACT == 1) val = 0.5f * val * (1.f + erff(val * 0.70710678118654752f));
            if (RES == 1) val += C[crow + n];
            else if (RES == 2) val += R[crow + n];
            C[crow + n] = val;
        }
    }
}

// ---------------- bf16 MFMA GEMM: C[M,N] = A[M,K] @ Bw[N,K]^T (+bias,+res,gelu) ----------------
// APERM: A row m is read from row ((m&255)<<8)|(m>>8) (M must be 65536).
// RES: 0 none, 1 += C in place, 2 += R.  ACT: exact GELU.  OUTBF: store bf16 to Cb.
template <int APERM, int RES, int ACT, int OUTBF>
__global__ __launch_bounds__(256) void mgemm_kernel(const bf16_t* __restrict__ A,
                                                    const bf16_t* __restrict__ Bw,
                                                    const float* __restrict__ bias,
                                                    const float* __restrict__ R,
                                                    float* __restrict__ C,
                                                    bf16_t* __restrict__ Cb,
                                                    int M, int N, int K) {
    __shared__ bf16_t As[128 * 40];  // row stride 40 bf16 = 80 B (16B-aligned, bank step 20)
    __shared__ bf16_t Bs[128 * 40];
    int tid = threadIdx.x;
    int bm = blockIdx.y * 128, bn = blockIdx.x * 128;
    int lane = tid & 63, wvid = tid >> 6;
    int wm = (wvid >> 1) * 64, wn = (wvid & 1) * 64;
    int lrow = lane & 15, lchunk = lane >> 4;

    f32x4 acc[4][4];
#pragma unroll
    for (int i = 0; i < 4; i++)
#pragma unroll
        for (int j = 0; j < 4; j++) acc[i][j] = (f32x4){0.f, 0.f, 0.f, 0.f};

    // staging: thread t loads 16B chunks (8 bf16) for rows r0 and r0+64, chunk c0
    int r0 = tid >> 2, c0 = tid & 3;
    int ra0 = bm + r0, ra1 = bm + r0 + 64;
    if (APERM) {
        ra0 = ((ra0 & 255) << 8) | (ra0 >> 8);
        ra1 = ((ra1 & 255) << 8) | (ra1 >> 8);
    }
    size_t sa0 = (size_t)ra0 * K, sa1 = (size_t)ra1 * K;
    size_t sb0 = (size_t)(bn + r0) * K, sb1 = (size_t)(bn + r0 + 64) * K;

    for (int k0 = 0; k0 < K; k0 += 32) {
        uint4 va0 = *(const uint4*)(A + sa0 + k0 + c0 * 8);
        uint4 va1 = *(const uint4*)(A + sa1 + k0 + c0 * 8);
        uint4 vb0 = *(const uint4*)(Bw + sb0 + k0 + c0 * 8);
        uint4 vb1 = *(const uint4*)(Bw + sb1 + k0 + c0 * 8);
        __syncthreads();
        *(uint4*)&As[r0 * 40 + c0 * 8] = va0;
        *(uint4*)&As[(r0 + 64) * 40 + c0 * 8] = va1;
        *(uint4*)&Bs[r0 * 40 + c0 * 8] = vb0;
        *(uint4*)&Bs[(r0 + 64) * 40 + c0 * 8] = vb1;
        __syncthreads();
        bf16x8 af[4], bfr[4];
#pragma unroll
        for (int f = 0; f < 4; f++) {
            af[f] = *(const bf16x8*)&As[(wm + f * 16 + lrow) * 40 + lchunk * 8];
            bfr[f] = *(const bf16x8*)&Bs[(wn + f * 16 + lrow) * 40 + lchunk * 8];
        }
#pragma unroll
        for (int fi = 0; fi < 4; fi++)
#pragma unroll
            for (int fj = 0; fj < 4; fj++)
                acc[fi][fj] = __builtin_amdgcn_mfma_f32_16x16x32_bf16(af[fi], bfr[fj], acc[fi][fj], 0, 0, 0);
    }
    // C/D layout: col = lane&15, row = (lane>>4)*4 + reg
#pragma unroll
    for (int fi = 0; fi < 4; fi++) {
#pragma unroll
        for (int i = 0; i < 4; i++) {
            int gm = bm + wm + fi * 16 + lchunk * 4 + i;
            size_t crow = (size_t)gm * N;
#pragma unroll
            for (int fj = 0; fj < 4; fj++) {
                int gn = bn + wn + fj * 16 + lrow;
                float val = acc[fi][fj][i];
                if (bias) val += bias[gn];
                if (ACT == 1) val = 0.5f * val * (1.f + erff(val * 0.70710678118654752f));
                if (RES == 1) val += C[crow + gn];
                else if (RES == 2) val += R[crow + gn];
                if (OUTBF) Cb[crow + gn] = (bf16_t)val;
                else C[crow + gn] = val;
            }
        }
    }
}

// ---------------- weight conversion ----------------
__global__ void cast_bf16_kernel(const float* __restrict__ in, bf16_t* __restrict__ out, int n) {
    int i = blockIdx.x * 256 + threadIdx.x;
    if (i < n) out[i] = (bf16_t)in[i];
}
// in (K,N) row-major -> out (N,K) row-major bf16
__global__ void transpose_bf16_kernel(const float* __restrict__ in, bf16_t* __restrict__ out,
                                      int K, int N) {
    int i = blockIdx.x * 256 + threadIdx.x;
    if (i < K * N) {
        int k = i / N, n = i % N;
        out[(size_t)n * K + k] = (bf16_t)in[i];
    }
}

// ---------------- outer-sum: z[i,j,:] += a[i,:] + b[j,:] ----------------
__global__ void outer_add_kernel(float* __restrict__ z, const float* __restrict__ a,
                                 const float* __restrict__ b) {
    size_t idx = (size_t)blockIdx.x * blockDim.x + threadIdx.x;
    size_t e = idx * 4;
    int c4 = (int)(e & 127);
    int pair = (int)(e >> 7);
    int i = pair >> 8, j = pair & 255;
    float4 zv = *(float4*)(z + e);
    float4 avv = *(const float4*)(a + (size_t)i * 128 + c4);
    float4 bvv = *(const float4*)(b + (size_t)j * 128 + c4);
    zv.x += avv.x + bvv.x;
    zv.y += avv.y + bvv.y;
    zv.z += avv.z + bvv.z;
    zv.w += avv.w + bvv.w;
    *(float4*)(z + e) = zv;
}

extern "C" void kernel_launch(void* const* d_in, const int* in_sizes, int n_in,
                              void* d_out, int out_size, void* d_ws, size_t ws_size,
                              hipStream_t stream) {
    const float* s_in = (const float*)d_in[0];
    const float* z_in = (const float*)d_in[1];
    const float* sng = (const float*)d_in[3];
    const float* snb = (const float*)d_in[4];
    const float* zng = (const float*)d_in[5];
    const float* znb = (const float*)d_in[6];
    const float* wq = (const float*)d_in[7];
    const float* bq = (const float*)d_in[8];
    const float* wk = (const float*)d_in[9];
    const float* bk = (const float*)d_in[10];
    const float* wv = (const float*)d_in[11];
    const float* bv = (const float*)d_in[12];
    const float* wzb = (const float*)d_in[13];
    const float* bzb = (const float*)d_in[14];
    const float* wo = (const float*)d_in[15];
    const float* bo = (const float*)d_in[16];
    const float* sffw1 = (const float*)d_in[17];
    const float* sffb1 = (const float*)d_in[18];
    const float* sffw2 = (const float*)d_in[19];
    const float* sffb2 = (const float*)d_in[20];
    const float* pzg = (const float*)d_in[21];
    const float* pzb = (const float*)d_in[22];
    const float* rinw = (const float*)d_in[23];
    const float* rinb = (const float*)d_in[24];
    const float* routw = (const float*)d_in[25];
    const float* routb = (const float*)d_in[26];
    const float* cinw = (const float*)d_in[27];
    const float* cinb = (const float*)d_in[28];
    const float* coutw = (const float*)d_in[29];
    const float* coutb = (const float*)d_in[30];
    const float* sziw = (const float*)d_in[31];
    const float* szjw = (const float*)d_in[32];
    const float* zffw1 = (const float*)d_in[33];
    const float* zffb1 = (const float*)d_in[34];
    const float* zffw2 = (const float*)d_in[35];
    const float* zffb2 = (const float*)d_in[36];

    float* ws = (float*)d_ws;
    // big buffers
    float* qkv = ws;                               // 25,165,824 f
    bf16_t* hbf = (bf16_t*)ws;                     // 33,554,432 bf16, overlays qkv (dead)
    bf16_t* obbf = (bf16_t*)(ws + 25165824);       // 8,388,608 bf16
    bf16_t* znpbf = (bf16_t*)(ws + 29360128);      // 8,388,608 bf16 (reused for znf)
    // bf16 weights
    bf16_t* wrin = (bf16_t*)(ws + 33554432);       // 49152
    bf16_t* wcin = (bf16_t*)(ws + 33579008);       // 49152
    bf16_t* wrout = (bf16_t*)(ws + 33603584);      // 16384
    bf16_t* wcout = (bf16_t*)(ws + 33611776);      // 16384
    bf16_t* wff1 = (bf16_t*)(ws + 33619968);       // 65536
    bf16_t* wff2 = (bf16_t*)(ws + 33652736);       // 65536
    // small fp32 buffers
    float* sn = ws + 33685504;
    float* qs = ws + 33783808;
    float* ks_ = ws + 33882112;
    float* vs_ = ws + 33980416;
    float* biasb = ws + 34078720;                  // 524288
    float* os_ = ws + 34603008;
    float* s1 = ws + 34701312;
    float* sn2 = ws + 34799616;
    float* hs = ws + 34897920;                     // 393216
    float* sn3 = ws + 35291136;
    float* aout = ws + 35389440;
    float* bout = ws + 35422208;

    float* sout = (float*)d_out;
    float* zout = sout + 98304;

    dim3 b256(256);
    dim3 b128(128);

    // --- weight conversions (independent, cheap) ---
    cast_bf16_kernel<<<dim3(192), b256, 0, stream>>>(rinw, wrin, 49152);
    cast_bf16_kernel<<<dim3(192), b256, 0, stream>>>(cinw, wcin, 49152);
    cast_bf16_kernel<<<dim3(64), b256, 0, stream>>>(routw, wrout, 16384);
    cast_bf16_kernel<<<dim3(64), b256, 0, stream>>>(coutw, wcout, 16384);
    transpose_bf16_kernel<<<dim3(256), b256, 0, stream>>>(zffw1, wff1, 128, 512);
    transpose_bf16_kernel<<<dim3(256), b256, 0, stream>>>(zffw2, wff2, 512, 128);

    // --- s attention ---
    ln_kernel<float><<<dim3(LL), dim3(CSD), 0, stream>>>(s_in, sng, snb, sn, CSD);
    zbias_kernel<<<dim3(65536), b128, 0, stream>>>(z_in, zng, znb, wzb, bzb, biasb);
    gemm_kernel<0, 0><<<dim3(6, 4), b256, 0, stream>>>(sn, wq, bq, nullptr, qs, 256, CSD, CSD);
    gemm_kernel<0, 0><<<dim3(6, 4), b256, 0, stream>>>(sn, wk, bk, nullptr, ks_, 256, CSD, CSD);
    gemm_kernel<0, 0><<<dim3(6, 4), b256, 0, stream>>>(sn, wv, bv, nullptr, vs_, 256, CSD, CSD);
    sattn_kernel<<<dim3(LL, HNUM), b256, 0, stream>>>(qs, ks_, vs_, biasb, os_);
    gemm_kernel<2, 0><<<dim3(6, 4), b256, 0, stream>>>(os_, wo, bo, s_in, s1, 256, CSD, CSD);
    // --- s feedforward ---
    ln_kernel<float><<<dim3(LL), dim3(CSD), 0, stream>>>(s1, sng, snb, sn2, CSD);
    gemm_kernel<0, 1><<<dim3(24, 4), b256, 0, stream>>>(sn2, sffw1, sffb1, nullptr, hs, 256, 1536, CSD);
    gemm_kernel<2, 0><<<dim3(6, 4), b256, 0, stream>>>(hs, sffw2, sffb2, s1, sout, 256, CSD, 1536);
    // --- pair LN (bf16 out) ---
    ln_kernel<bf16_t><<<dim3(65536), b128, 0, stream>>>(z_in, pzg, pzb, znpbf, CZD);
    // --- row attention ---
    mgemm_kernel<0, 0, 0, 0><<<dim3(3, 512), b256, 0, stream>>>(znpbf, wrin, rinb, nullptr, qkv, nullptr, 65536, 384, CZD);
    pattn_kernel<<<dim3(256, HNUM), b256, 0, stream>>>(qkv, obbf);
    mgemm_kernel<0, 2, 0, 0><<<dim3(1, 512), b256, 0, stream>>>(obbf, wrout, routb, z_in, zout, nullptr, 65536, CZD, CZD);
    // --- col attention ---
    mgemm_kernel<1, 0, 0, 0><<<dim3(3, 512), b256, 0, stream>>>(znpbf, wcin, cinb, nullptr, qkv, nullptr, 65536, 384, CZD);
    pattn_kernel<<<dim3(256, HNUM), b256, 0, stream>>>(qkv, obbf);
    mgemm_kernel<1, 1, 0, 0><<<dim3(1, 512), b256, 0, stream>>>(obbf, wcout, coutb, nullptr, zout, nullptr, 65536, CZD, CZD);
    // --- outer sum ---
    ln_kernel<float><<<dim3(LL), dim3(CSD), 0, stream>>>(sout, sng, snb, sn3, CSD);
    gemm_kernel<0, 0><<<dim3(2, 4), b256, 0, stream>>>(sn3, sziw, nullptr, nullptr, aout, 256, CZD, CSD);
    gemm_kernel<0, 0><<<dim3(2, 4), b256, 0, stream>>>(sn3, szjw, nullptr, nullptr, bout, 256, CZD, CSD);
    outer_add_kernel<<<dim3(8192), b256, 0, stream>>>(zout, aout, bout);
    // --- z feedforward ---
    ln_kernel<bf16_t><<<dim3(65536), b128, 0, stream>>>(zout, zng, znb, znpbf, CZD);
    mgemm_kernel<0, 0, 1, 1><<<dim3(4, 512), b256, 0, stream>>>(znpbf, wff1, zffb1, nullptr, nullptr, hbf, 65536, 512, CZD);
    mgemm_kernel<0, 1, 0, 0><<<dim3(1, 512), b256, 0, stream>>>(hbf, wff2, zffb2, nullptr, zout, nullptr, 65536, CZD, 512);
}

// Round 3
// 995.145 us; speedup vs baseline: 1.8029x; 1.1814x over previous
//
#include <hip/hip_runtime.h>
#include <math.h>

#define LL 256
#define CSD 384
#define CZD 128
#define HNUM 8
#define DHS 48
#define DHZ 16

typedef __bf16 bf16_t;
typedef bf16_t bf16x8 __attribute__((ext_vector_type(8)));
typedef float f32x4 __attribute__((ext_vector_type(4)));
typedef float f32x16 __attribute__((ext_vector_type(16)));

// ---------------- LayerNorm: one block per row, blockDim.x == W ----------------
template <typename OUT>
__global__ void ln_kernel(const float* __restrict__ x, const float* __restrict__ g,
                          const float* __restrict__ b, OUT* __restrict__ y, int W) {
    size_t row = blockIdx.x;
    int t = threadIdx.x;
    float v = x[row * (size_t)W + t];
    float s = v, s2 = v * v;
#pragma unroll
    for (int o = 32; o > 0; o >>= 1) { s += __shfl_down(s, o); s2 += __shfl_down(s2, o); }
    __shared__ float sh[8], sh2[8];
    int w = t >> 6, nw = W >> 6;
    if ((t & 63) == 0) { sh[w] = s; sh2[w] = s2; }
    __syncthreads();
    if (t == 0) {
        float a = 0, a2 = 0;
        for (int i = 0; i < nw; i++) { a += sh[i]; a2 += sh2[i]; }
        sh[0] = a; sh2[0] = a2;
    }
    __syncthreads();
    float mean = sh[0] / W;
    float var = sh2[0] / W - mean * mean;
    y[row * (size_t)W + t] = (OUT)((v - mean) * rsqrtf(var + 1e-5f) * g[t] + b[t]);
}

// ---------------- pair bias: per pair LN(z)*wzb -> bias[h][i][j] ----------------
__global__ void zbias_kernel(const float* __restrict__ z, const float* __restrict__ g,
                             const float* __restrict__ b, const float* __restrict__ wzb,
                             const float* __restrict__ bzb, float* __restrict__ bias) {
    int p = blockIdx.x;      // i*256+j
    int t = threadIdx.x;     // 0..127
    float v = z[(size_t)p * CZD + t];
    float s = v, s2 = v * v;
#pragma unroll
    for (int o = 32; o > 0; o >>= 1) { s += __shfl_down(s, o); s2 += __shfl_down(s2, o); }
    __shared__ float sh[2], sh2[2];
    if ((t & 63) == 0) { sh[t >> 6] = s; sh2[t >> 6] = s2; }
    __syncthreads();
    float mean = (sh[0] + sh[1]) / 128.f;
    float var = (sh2[0] + sh2[1]) / 128.f - mean * mean;
    float zn = (v - mean) * rsqrtf(var + 1e-5f) * g[t] + b[t];
    float pr[8];
#pragma unroll
    for (int hh = 0; hh < 8; hh++) pr[hh] = zn * wzb[t * 8 + hh];
#pragma unroll
    for (int off = 32; off > 0; off >>= 1)
#pragma unroll
        for (int hh = 0; hh < 8; hh++) pr[hh] += __shfl_down(pr[hh], off);
    __shared__ float red[2][8];
    if ((t & 63) == 0)
#pragma unroll
        for (int hh = 0; hh < 8; hh++) red[t >> 6][hh] = pr[hh];
    __syncthreads();
    if (t < 8) bias[(size_t)t * 65536 + p] = red[0][t] + red[1][t] + bzb[t];
}

// ---------------- s-track attention: one block per (query l, head h) ----------------
__global__ void sattn_kernel(const float* __restrict__ q, const float* __restrict__ k,
                             const float* __restrict__ v, const float* __restrict__ bias,
                             float* __restrict__ o) {
    int l = blockIdx.x, h = blockIdx.y;
    int m = threadIdx.x;  // 256 keys
    const float* qr = q + (size_t)l * CSD + h * DHS;
    const float* kr = k + (size_t)m * CSD + h * DHS;
    float acc = 0.f;
#pragma unroll
    for (int d = 0; d < DHS; d++) acc += qr[d] * kr[d];
    acc = acc * 0.14433756729740643f + bias[(size_t)h * 65536 + l * 256 + m];

    __shared__ float attn[256];
    __shared__ float redm[4], reds[4];
    float x = acc;
#pragma unroll
    for (int off = 32; off > 0; off >>= 1) x = fmaxf(x, __shfl_down(x, off));
    if ((m & 63) == 0) redm[m >> 6] = x;
    __syncthreads();
    float mx = fmaxf(fmaxf(redm[0], redm[1]), fmaxf(redm[2], redm[3]));
    float p = __expf(acc - mx);
    float ss = p;
#pragma unroll
    for (int off = 32; off > 0; off >>= 1) ss += __shfl_down(ss, off);
    if ((m & 63) == 0) reds[m >> 6] = ss;
    __syncthreads();
    float sum = reds[0] + reds[1] + reds[2] + reds[3];
    attn[m] = p / sum;
    __syncthreads();
    if (m < DHS) {
        float a = 0.f;
        for (int j = 0; j < 256; j++) a += attn[j] * v[(size_t)j * CSD + h * DHS + m];
        o[(size_t)l * CSD + h * DHS + m] = a;
    }
}

// ---------------- MFMA pair attention: one block per (n,h), 4 waves x 2 chunks of 32 q ----
// qkv is bf16, row = token (n*256+t), cols [q(128)|k(128)|v(128)], head slice h*16.
// Single-pass softmax (|logit|<~2): O = exp(S/4) @ [V | 1] ; col16 gives the row-sum.
__global__ __launch_bounds__(256) void pattn_mfma_kernel(const bf16_t* __restrict__ qkv,
                                                         bf16_t* __restrict__ o) {
    int n = blockIdx.x, h = blockIdx.y;
    int tid = threadIdx.x;
    __shared__ bf16_t Qs[256 * 24];   // row stride 24 elems (48B, bank-spread, 16B aligned)
    __shared__ bf16_t Ks[256 * 24];
    __shared__ bf16_t Vt[32 * 264];   // transposed V, row stride 264 (528B); row16 = ones
    __shared__ bf16_t Ps[4][32 * 72]; // per-wave P, row stride 72 (144B)

    {
        const bf16_t* row = qkv + ((size_t)n * 256 + tid) * 384 + h * 16;
        uint4 q0 = *(const uint4*)(row);
        uint4 q1 = *(const uint4*)(row + 8);
        uint4 k0 = *(const uint4*)(row + 128);
        uint4 k1 = *(const uint4*)(row + 136);
        uint4 v0 = *(const uint4*)(row + 256);
        uint4 v1 = *(const uint4*)(row + 264);
        *(uint4*)&Qs[tid * 24] = q0; *(uint4*)&Qs[tid * 24 + 8] = q1;
        *(uint4*)&Ks[tid * 24] = k0; *(uint4*)&Ks[tid * 24 + 8] = k1;
        bf16_t vv[16];
        *(uint4*)&vv[0] = v0; *(uint4*)&vv[8] = v1;
#pragma unroll
        for (int d = 0; d < 16; d++) Vt[d * 264 + tid] = vv[d];
        Vt[16 * 264 + tid] = (bf16_t)1.0f;
    }
    __syncthreads();

    int wv = tid >> 6, lane = tid & 63;
    int l5 = lane >> 5, l31 = lane & 31;
    bf16_t* P = &Ps[wv][0];
    const f32x16 zero16 = {0.f,0.f,0.f,0.f,0.f,0.f,0.f,0.f,0.f,0.f,0.f,0.f,0.f,0.f,0.f,0.f};

    for (int chunk = 0; chunk < 2; chunk++) {
        int q0i = wv * 64 + chunk * 32;
        bf16x8 aq = *(const bf16x8*)&Qs[(q0i + l31) * 24 + l5 * 8];
        f32x16 oacc = zero16;
        for (int kt = 0; kt < 4; kt++) {
#pragma unroll
            for (int ct2 = 0; ct2 < 2; ct2++) {
                int ct = kt * 2 + ct2;
                bf16x8 kb = *(const bf16x8*)&Ks[(ct * 32 + l31) * 24 + l5 * 8];
                f32x16 s = __builtin_amdgcn_mfma_f32_32x32x16_bf16(aq, kb, zero16, 0, 0, 0);
#pragma unroll
                for (int r = 0; r < 16; r++) {
                    float p = __expf(0.25f * s[r]);
                    int prow = (r & 3) + 8 * (r >> 2) + 4 * l5;
                    P[prow * 72 + ct2 * 32 + l31] = (bf16_t)p;
                }
            }
#pragma unroll
            for (int st = 0; st < 4; st++) {
                bf16x8 pa = *(const bf16x8*)&P[l31 * 72 + st * 16 + l5 * 8];
                bf16x8 vb = *(const bf16x8*)&Vt[l31 * 264 + kt * 64 + st * 16 + l5 * 8];
                oacc = __builtin_amdgcn_mfma_f32_32x32x16_bf16(pa, vb, oacc, 0, 0, 0);
            }
        }
        // epilogue: col16 of oacc = row-sum; divide; store cols 0..15
#pragma unroll
        for (int r = 0; r < 16; r++) {
            float v = oacc[r];
            float sum = __shfl(v, (lane & 32) + 16, 64);
            int prow = (r & 3) + 8 * (r >> 2) + 4 * l5;
            if (l31 < 16)
                o[((size_t)n * 256 + q0i + prow) * CZD + h * 16 + l31] = (bf16_t)(v / sum);
        }
    }
}

// ---------------- fp32 tiled GEMM (small s-track mats only) ----------------
template <int RES, int ACT>
__global__ __launch_bounds__(256) void gemm_kernel(const float* __restrict__ A,
                                                   const float* __restrict__ B,
                                                   const float* __restrict__ bias,
                                                   const float* __restrict__ R,
                                                   float* __restrict__ C,
                                                   int M, int N, int K) {
    __shared__ float As[64][17];
    __shared__ float Bs[16][65];
    int tid = threadIdx.x;
    int bm = blockIdx.y * 64, bn = blockIdx.x * 64;
    int tx = tid & 15, ty = tid >> 4;
    float acc[4][4] = {};
    int arow = bm + (tid >> 2);
    size_t aoff = (size_t)arow * K;
    int ak = (tid & 3) * 4;
    for (int k0 = 0; k0 < K; k0 += 16) {
        float4 av = *(const float4*)(A + aoff + k0 + ak);
        As[tid >> 2][ak + 0] = av.x;
        As[tid >> 2][ak + 1] = av.y;
        As[tid >> 2][ak + 2] = av.z;
        As[tid >> 2][ak + 3] = av.w;
        int bk = tid >> 4;
        int bn_l = (tid & 15) * 4;
        float4 bv = *(const float4*)(B + (size_t)(k0 + bk) * N + bn + bn_l);
        Bs[bk][bn_l + 0] = bv.x;
        Bs[bk][bn_l + 1] = bv.y;
        Bs[bk][bn_l + 2] = bv.z;
        Bs[bk][bn_l + 3] = bv.w;
        __syncthreads();
#pragma unroll
        for (int kk = 0; kk < 16; kk++) {
            float a[4], b[4];
#pragma unroll
            for (int i = 0; i < 4; i++) a[i] = As[ty * 4 + i][kk];
#pragma unroll
            for (int j = 0; j < 4; j++) b[j] = Bs[kk][tx * 4 + j];
#pragma unroll
            for (int i = 0; i < 4; i++)
#pragma unroll
                for (int j = 0; j < 4; j++) acc[i][j] += a[i] * b[j];
        }
        __syncthreads();
    }
#pragma unroll
    for (int i = 0; i < 4; i++) {
        int m = bm + ty * 4 + i;
        size_t crow = (size_t)m * N;
#pragma unroll
        for (int j = 0; j < 4; j++) {
            int n = bn + tx * 4 + j;
            float val = acc[i][j];
            if (bias) val += bias[n];
            if (ACT == 1) val = 0.5f * val * (1.f + erff(val * 0.70710678118654752f));
            if (RES == 1) val += C[crow + n];
            else if (RES == 2) val += R[crow + n];
            C[crow + n] = val;
        }
    }
}

// ---------------- bf16 MFMA GEMM: C[M,N] = A[M,K] @ Bw[N,K]^T (+bias,+res,gelu) ----------------
template <int APERM, int RES, int ACT, int OUTBF>
__global__ __launch_bounds__(256) void mgemm_kernel(const bf16_t* __restrict__ A,
                                                    const bf16_t* __restrict__ Bw,
                                                    const float* __restrict__ bias,
                                                    const float* __restrict__ R,
                                                    float* __restrict__ C,
                                                    bf16_t* __restrict__ Cb,
                                                    int M, int N, int K) {
    __shared__ bf16_t As[128 * 40];
    __shared__ bf16_t Bs[128 * 40];
    int tid = threadIdx.x;
    int bm = blockIdx.y * 128, bn = blockIdx.x * 128;
    int lane = tid & 63, wvid = tid >> 6;
    int wm = (wvid >> 1) * 64, wn = (wvid & 1) * 64;
    int lrow = lane & 15, lchunk = lane >> 4;

    f32x4 acc[4][4];
#pragma unroll
    for (int i = 0; i < 4; i++)
#pragma unroll
        for (int j = 0; j < 4; j++) acc[i][j] = (f32x4){0.f, 0.f, 0.f, 0.f};

    int r0 = tid >> 2, c0 = tid & 3;
    int ra0 = bm + r0, ra1 = bm + r0 + 64;
    if (APERM) {
        ra0 = ((ra0 & 255) << 8) | (ra0 >> 8);
        ra1 = ((ra1 & 255) << 8) | (ra1 >> 8);
    }
    size_t sa0 = (size_t)ra0 * K, sa1 = (size_t)ra1 * K;
    size_t sb0 = (size_t)(bn + r0) * K, sb1 = (size_t)(bn + r0 + 64) * K;

    for (int k0 = 0; k0 < K; k0 += 32) {
        uint4 va0 = *(const uint4*)(A + sa0 + k0 + c0 * 8);
        uint4 va1 = *(const uint4*)(A + sa1 + k0 + c0 * 8);
        uint4 vb0 = *(const uint4*)(Bw + sb0 + k0 + c0 * 8);
        uint4 vb1 = *(const uint4*)(Bw + sb1 + k0 + c0 * 8);
        __syncthreads();
        *(uint4*)&As[r0 * 40 + c0 * 8] = va0;
        *(uint4*)&As[(r0 + 64) * 40 + c0 * 8] = va1;
        *(uint4*)&Bs[r0 * 40 + c0 * 8] = vb0;
        *(uint4*)&Bs[(r0 + 64) * 40 + c0 * 8] = vb1;
        __syncthreads();
        bf16x8 af[4], bfr[4];
#pragma unroll
        for (int f = 0; f < 4; f++) {
            af[f] = *(const bf16x8*)&As[(wm + f * 16 + lrow) * 40 + lchunk * 8];
            bfr[f] = *(const bf16x8*)&Bs[(wn + f * 16 + lrow) * 40 + lchunk * 8];
        }
#pragma unroll
        for (int fi = 0; fi < 4; fi++)
#pragma unroll
            for (int fj = 0; fj < 4; fj++)
                acc[fi][fj] = __builtin_amdgcn_mfma_f32_16x16x32_bf16(af[fi], bfr[fj], acc[fi][fj], 0, 0, 0);
    }
#pragma unroll
    for (int fi = 0; fi < 4; fi++) {
#pragma unroll
        for (int i = 0; i < 4; i++) {
            int gm = bm + wm + fi * 16 + lchunk * 4 + i;
            size_t crow = (size_t)gm * N;
#pragma unroll
            for (int fj = 0; fj < 4; fj++) {
                int gn = bn + wn + fj * 16 + lrow;
                float val = acc[fi][fj][i];
                if (bias) val += bias[gn];
                if (ACT == 1) val = 0.5f * val * (1.f + erff(val * 0.70710678118654752f));
                if (RES == 1) val += C[crow + gn];
                else if (RES == 2) val += R[crow + gn];
                if (OUTBF) Cb[crow + gn] = (bf16_t)val;
                else C[crow + gn] = val;
            }
        }
    }
}

// ---------------- weight conversion ----------------
__global__ void cast_bf16_kernel(const float* __restrict__ in, bf16_t* __restrict__ out, int n) {
    int i = blockIdx.x * 256 + threadIdx.x;
    if (i < n) out[i] = (bf16_t)in[i];
}
__global__ void transpose_bf16_kernel(const float* __restrict__ in, bf16_t* __restrict__ out,
                                      int K, int N) {
    int i = blockIdx.x * 256 + threadIdx.x;
    if (i < K * N) {
        int k = i / N, n = i % N;
        out[(size_t)n * K + k] = (bf16_t)in[i];
    }
}

// ---------------- outer-sum: z[i,j,:] += a[i,:] + b[j,:] ----------------
__global__ void outer_add_kernel(float* __restrict__ z, const float* __restrict__ a,
                                 const float* __restrict__ b) {
    size_t idx = (size_t)blockIdx.x * blockDim.x + threadIdx.x;
    size_t e = idx * 4;
    int c4 = (int)(e & 127);
    int pair = (int)(e >> 7);
    int i = pair >> 8, j = pair & 255;
    float4 zv = *(float4*)(z + e);
    float4 avv = *(const float4*)(a + (size_t)i * 128 + c4);
    float4 bvv = *(const float4*)(b + (size_t)j * 128 + c4);
    zv.x += avv.x + bvv.x;
    zv.y += avv.y + bvv.y;
    zv.z += avv.z + bvv.z;
    zv.w += avv.w + bvv.w;
    *(float4*)(z + e) = zv;
}

extern "C" void kernel_launch(void* const* d_in, const int* in_sizes, int n_in,
                              void* d_out, int out_size, void* d_ws, size_t ws_size,
                              hipStream_t stream) {
    const float* s_in = (const float*)d_in[0];
    const float* z_in = (const float*)d_in[1];
    const float* sng = (const float*)d_in[3];
    const float* snb = (const float*)d_in[4];
    const float* zng = (const float*)d_in[5];
    const float* znb = (const float*)d_in[6];
    const float* wq = (const float*)d_in[7];
    const float* bq = (const float*)d_in[8];
    const float* wk = (const float*)d_in[9];
    const float* bk = (const float*)d_in[10];
    const float* wv = (const float*)d_in[11];
    const float* bv = (const float*)d_in[12];
    const float* wzb = (const float*)d_in[13];
    const float* bzb = (const float*)d_in[14];
    const float* wo = (const float*)d_in[15];
    const float* bo = (const float*)d_in[16];
    const float* sffw1 = (const float*)d_in[17];
    const float* sffb1 = (const float*)d_in[18];
    const float* sffw2 = (const float*)d_in[19];
    const float* sffb2 = (const float*)d_in[20];
    const float* pzg = (const float*)d_in[21];
    const float* pzb = (const float*)d_in[22];
    const float* rinw = (const float*)d_in[23];
    const float* rinb = (const float*)d_in[24];
    const float* routw = (const float*)d_in[25];
    const float* routb = (const float*)d_in[26];
    const float* cinw = (const float*)d_in[27];
    const float* cinb = (const float*)d_in[28];
    const float* coutw = (const float*)d_in[29];
    const float* coutb = (const float*)d_in[30];
    const float* sziw = (const float*)d_in[31];
    const float* szjw = (const float*)d_in[32];
    const float* zffw1 = (const float*)d_in[33];
    const float* zffb1 = (const float*)d_in[34];
    const float* zffw2 = (const float*)d_in[35];
    const float* zffb2 = (const float*)d_in[36];

    float* ws = (float*)d_ws;
    // region [0, 25165824) floats: qkvbf (bf16 65536x384 = 12.6M floats) / hbf (bf16 65536x512)
    bf16_t* qkvbf = (bf16_t*)ws;
    bf16_t* hbf = (bf16_t*)ws;
    bf16_t* obbf = (bf16_t*)(ws + 25165824);       // 8,388,608 bf16
    bf16_t* znpbf = (bf16_t*)(ws + 29360128);      // 8,388,608 bf16
    bf16_t* wrin = (bf16_t*)(ws + 33554432);
    bf16_t* wcin = (bf16_t*)(ws + 33579008);
    bf16_t* wrout = (bf16_t*)(ws + 33603584);
    bf16_t* wcout = (bf16_t*)(ws + 33611776);
    bf16_t* wff1 = (bf16_t*)(ws + 33619968);
    bf16_t* wff2 = (bf16_t*)(ws + 33652736);
    float* sn = ws + 33685504;
    float* qs = ws + 33783808;
    float* ks_ = ws + 33882112;
    float* vs_ = ws + 33980416;
    float* biasb = ws + 34078720;
    float* os_ = ws + 34603008;
    float* s1 = ws + 34701312;
    float* sn2 = ws + 34799616;
    float* hs = ws + 34897920;
    float* sn3 = ws + 35291136;
    float* aout = ws + 35389440;
    float* bout = ws + 35422208;

    float* sout = (float*)d_out;
    float* zout = sout + 98304;

    dim3 b256(256);
    dim3 b128(128);

    // --- weight conversions ---
    cast_bf16_kernel<<<dim3(192), b256, 0, stream>>>(rinw, wrin, 49152);
    cast_bf16_kernel<<<dim3(192), b256, 0, stream>>>(cinw, wcin, 49152);
    cast_bf16_kernel<<<dim3(64), b256, 0, stream>>>(routw, wrout, 16384);
    cast_bf16_kernel<<<dim3(64), b256, 0, stream>>>(coutw, wcout, 16384);
    transpose_bf16_kernel<<<dim3(256), b256, 0, stream>>>(zffw1, wff1, 128, 512);
    transpose_bf16_kernel<<<dim3(256), b256, 0, stream>>>(zffw2, wff2, 512, 128);

    // --- s attention ---
    ln_kernel<float><<<dim3(LL), dim3(CSD), 0, stream>>>(s_in, sng, snb, sn, CSD);
    zbias_kernel<<<dim3(65536), b128, 0, stream>>>(z_in, zng, znb, wzb, bzb, biasb);
    gemm_kernel<0, 0><<<dim3(6, 4), b256, 0, stream>>>(sn, wq, bq, nullptr, qs, 256, CSD, CSD);
    gemm_kernel<0, 0><<<dim3(6, 4), b256, 0, stream>>>(sn, wk, bk, nullptr, ks_, 256, CSD, CSD);
    gemm_kernel<0, 0><<<dim3(6, 4), b256, 0, stream>>>(sn, wv, bv, nullptr, vs_, 256, CSD, CSD);
    sattn_kernel<<<dim3(LL, HNUM), b256, 0, stream>>>(qs, ks_, vs_, biasb, os_);
    gemm_kernel<2, 0><<<dim3(6, 4), b256, 0, stream>>>(os_, wo, bo, s_in, s1, 256, CSD, CSD);
    // --- s feedforward ---
    ln_kernel<float><<<dim3(LL), dim3(CSD), 0, stream>>>(s1, sng, snb, sn2, CSD);
    gemm_kernel<0, 1><<<dim3(24, 4), b256, 0, stream>>>(sn2, sffw1, sffb1, nullptr, hs, 256, 1536, CSD);
    gemm_kernel<2, 0><<<dim3(6, 4), b256, 0, stream>>>(hs, sffw2, sffb2, s1, sout, 256, CSD, 1536);
    // --- pair LN (bf16 out) ---
    ln_kernel<bf16_t><<<dim3(65536), b128, 0, stream>>>(z_in, pzg, pzb, znpbf, CZD);
    // --- row attention ---
    mgemm_kernel<0, 0, 0, 1><<<dim3(3, 512), b256, 0, stream>>>(znpbf, wrin, rinb, nullptr, nullptr, qkvbf, 65536, 384, CZD);
    pattn_mfma_kernel<<<dim3(256, HNUM), b256, 0, stream>>>(qkvbf, obbf);
    mgemm_kernel<0, 2, 0, 0><<<dim3(1, 512), b256, 0, stream>>>(obbf, wrout, routb, z_in, zout, nullptr, 65536, CZD, CZD);
    // --- col attention ---
    mgemm_kernel<1, 0, 0, 1><<<dim3(3, 512), b256, 0, stream>>>(znpbf, wcin, cinb, nullptr, nullptr, qkvbf, 65536, 384, CZD);
    pattn_mfma_kernel<<<dim3(256, HNUM), b256, 0, stream>>>(qkvbf, obbf);
    mgemm_kernel<1, 1, 0, 0><<<dim3(1, 512), b256, 0, stream>>>(obbf, wcout, coutb, nullptr, zout, nullptr, 65536, CZD, CZD);
    // --- outer sum ---
    ln_kernel<float><<<dim3(LL), dim3(CSD), 0, stream>>>(sout, sng, snb, sn3, CSD);
    gemm_kernel<0, 0><<<dim3(2, 4), b256, 0, stream>>>(sn3, sziw, nullptr, nullptr, aout, 256, CZD, CSD);
    gemm_kernel<0, 0><<<dim3(2, 4), b256, 0, stream>>>(sn3, szjw, nullptr, nullptr, bout, 256, CZD, CSD);
    outer_add_kernel<<<dim3(8192), b256, 0, stream>>>(zout, aout, bout);
    // --- z feedforward ---
    ln_kernel<bf16_t><<<dim3(65536), b128, 0, stream>>>(zout, zng, znb, znpbf, CZD);
    mgemm_kernel<0, 0, 1, 1><<<dim3(4, 512), b256, 0, stream>>>(znpbf, wff1, zffb1, nullptr, nullptr, hbf, 65536, 512, CZD);
    mgemm_kernel<0, 1, 0, 0><<<dim3(1, 512), b256, 0, stream>>>(hbf, wff2, zffb2, nullptr, zout, nullptr, 65536, CZD, 512);
}

// Round 4
// 731.491 us; speedup vs baseline: 2.4527x; 1.3604x over previous
//
#include <hip/hip_runtime.h>
#include <math.h>

#define LL 256
#define CSD 384
#define CZD 128
#define HNUM 8
#define DHS 48
#define DHZ 16

typedef __bf16 bf16_t;
typedef bf16_t bf16x8 __attribute__((ext_vector_type(8)));
typedef float f32x4 __attribute__((ext_vector_type(4)));
typedef float f32x16 __attribute__((ext_vector_type(16)));

// ---------------- LayerNorm: one block per row, blockDim.x == W ----------------
template <typename OUT>
__global__ void ln_kernel(const float* __restrict__ x, const float* __restrict__ g,
                          const float* __restrict__ b, OUT* __restrict__ y, int W) {
    size_t row = blockIdx.x;
    int t = threadIdx.x;
    float v = x[row * (size_t)W + t];
    float s = v, s2 = v * v;
#pragma unroll
    for (int o = 32; o > 0; o >>= 1) { s += __shfl_down(s, o); s2 += __shfl_down(s2, o); }
    __shared__ float sh[8], sh2[8];
    int w = t >> 6, nw = W >> 6;
    if ((t & 63) == 0) { sh[w] = s; sh2[w] = s2; }
    __syncthreads();
    if (t == 0) {
        float a = 0, a2 = 0;
        for (int i = 0; i < nw; i++) { a += sh[i]; a2 += sh2[i]; }
        sh[0] = a; sh2[0] = a2;
    }
    __syncthreads();
    float mean = sh[0] / W;
    float var = sh2[0] / W - mean * mean;
    y[row * (size_t)W + t] = (OUT)((v - mean) * rsqrtf(var + 1e-5f) * g[t] + b[t]);
}

// ---------------- pair bias: per pair LN(z)*wzb -> bias[h][i][j] ----------------
__global__ void zbias_kernel(const float* __restrict__ z, const float* __restrict__ g,
                             const float* __restrict__ b, const float* __restrict__ wzb,
                             const float* __restrict__ bzb, float* __restrict__ bias) {
    int p = blockIdx.x;      // i*256+j
    int t = threadIdx.x;     // 0..127
    float v = z[(size_t)p * CZD + t];
    float s = v, s2 = v * v;
#pragma unroll
    for (int o = 32; o > 0; o >>= 1) { s += __shfl_down(s, o); s2 += __shfl_down(s2, o); }
    __shared__ float sh[2], sh2[2];
    if ((t & 63) == 0) { sh[t >> 6] = s; sh2[t >> 6] = s2; }
    __syncthreads();
    float mean = (sh[0] + sh[1]) / 128.f;
    float var = (sh2[0] + sh2[1]) / 128.f - mean * mean;
    float zn = (v - mean) * rsqrtf(var + 1e-5f) * g[t] + b[t];
    float pr[8];
#pragma unroll
    for (int hh = 0; hh < 8; hh++) pr[hh] = zn * wzb[t * 8 + hh];
#pragma unroll
    for (int off = 32; off > 0; off >>= 1)
#pragma unroll
        for (int hh = 0; hh < 8; hh++) pr[hh] += __shfl_down(pr[hh], off);
    __shared__ float red[2][8];
    if ((t & 63) == 0)
#pragma unroll
        for (int hh = 0; hh < 8; hh++) red[t >> 6][hh] = pr[hh];
    __syncthreads();
    if (t < 8) bias[(size_t)t * 65536 + p] = red[0][t] + red[1][t] + bzb[t];
}

// ---------------- s-track attention: one block per (query l, head h) ----------------
// q/k/v packed in qkv_s (256 x 1152 fp32): [q|k|v] each 384 wide. Output bf16.
__global__ void sattn_kernel(const float* __restrict__ qkv, const float* __restrict__ bias,
                             bf16_t* __restrict__ o) {
    int l = blockIdx.x, h = blockIdx.y;
    int m = threadIdx.x;  // 256 keys
    const float* qr = qkv + (size_t)l * 1152 + h * DHS;
    const float* kr = qkv + (size_t)m * 1152 + 384 + h * DHS;
    float acc = 0.f;
#pragma unroll
    for (int d = 0; d < DHS; d++) acc += qr[d] * kr[d];
    acc = acc * 0.14433756729740643f + bias[(size_t)h * 65536 + l * 256 + m];

    __shared__ float attn[256];
    __shared__ float redm[4], reds[4];
    float x = acc;
#pragma unroll
    for (int off = 32; off > 0; off >>= 1) x = fmaxf(x, __shfl_down(x, off));
    if ((m & 63) == 0) redm[m >> 6] = x;
    __syncthreads();
    float mx = fmaxf(fmaxf(redm[0], redm[1]), fmaxf(redm[2], redm[3]));
    float p = __expf(acc - mx);
    float ss = p;
#pragma unroll
    for (int off = 32; off > 0; off >>= 1) ss += __shfl_down(ss, off);
    if ((m & 63) == 0) reds[m >> 6] = ss;
    __syncthreads();
    float sum = reds[0] + reds[1] + reds[2] + reds[3];
    attn[m] = p / sum;
    __syncthreads();
    if (m < DHS) {
        float a = 0.f;
        for (int j = 0; j < 256; j++) a += attn[j] * qkv[(size_t)j * 1152 + 768 + h * DHS + m];
        o[(size_t)l * CSD + h * DHS + m] = (bf16_t)a;
    }
}

// ---------------- MFMA pair attention (unchanged from R3) ----------------
__global__ __launch_bounds__(256) void pattn_mfma_kernel(const bf16_t* __restrict__ qkv,
                                                         bf16_t* __restrict__ o) {
    int n = blockIdx.x, h = blockIdx.y;
    int tid = threadIdx.x;
    __shared__ bf16_t Qs[256 * 24];
    __shared__ bf16_t Ks[256 * 24];
    __shared__ bf16_t Vt[32 * 264];
    __shared__ bf16_t Ps[4][32 * 72];

    {
        const bf16_t* row = qkv + ((size_t)n * 256 + tid) * 384 + h * 16;
        uint4 q0 = *(const uint4*)(row);
        uint4 q1 = *(const uint4*)(row + 8);
        uint4 k0 = *(const uint4*)(row + 128);
        uint4 k1 = *(const uint4*)(row + 136);
        uint4 v0 = *(const uint4*)(row + 256);
        uint4 v1 = *(const uint4*)(row + 264);
        *(uint4*)&Qs[tid * 24] = q0; *(uint4*)&Qs[tid * 24 + 8] = q1;
        *(uint4*)&Ks[tid * 24] = k0; *(uint4*)&Ks[tid * 24 + 8] = k1;
        bf16_t vv[16];
        *(uint4*)&vv[0] = v0; *(uint4*)&vv[8] = v1;
#pragma unroll
        for (int d = 0; d < 16; d++) Vt[d * 264 + tid] = vv[d];
        Vt[16 * 264 + tid] = (bf16_t)1.0f;
    }
    __syncthreads();

    int wv = tid >> 6, lane = tid & 63;
    int l5 = lane >> 5, l31 = lane & 31;
    bf16_t* P = &Ps[wv][0];
    const f32x16 zero16 = {0.f,0.f,0.f,0.f,0.f,0.f,0.f,0.f,0.f,0.f,0.f,0.f,0.f,0.f,0.f,0.f};

    for (int chunk = 0; chunk < 2; chunk++) {
        int q0i = wv * 64 + chunk * 32;
        bf16x8 aq = *(const bf16x8*)&Qs[(q0i + l31) * 24 + l5 * 8];
        f32x16 oacc = zero16;
        for (int kt = 0; kt < 4; kt++) {
#pragma unroll
            for (int ct2 = 0; ct2 < 2; ct2++) {
                int ct = kt * 2 + ct2;
                bf16x8 kb = *(const bf16x8*)&Ks[(ct * 32 + l31) * 24 + l5 * 8];
                f32x16 s = __builtin_amdgcn_mfma_f32_32x32x16_bf16(aq, kb, zero16, 0, 0, 0);
#pragma unroll
                for (int r = 0; r < 16; r++) {
                    float p = __expf(0.25f * s[r]);
                    int prow = (r & 3) + 8 * (r >> 2) + 4 * l5;
                    P[prow * 72 + ct2 * 32 + l31] = (bf16_t)p;
                }
            }
#pragma unroll
            for (int st = 0; st < 4; st++) {
                bf16x8 pa = *(const bf16x8*)&P[l31 * 72 + st * 16 + l5 * 8];
                bf16x8 vb = *(const bf16x8*)&Vt[l31 * 264 + kt * 64 + st * 16 + l5 * 8];
                oacc = __builtin_amdgcn_mfma_f32_32x32x16_bf16(pa, vb, oacc, 0, 0, 0);
            }
        }
#pragma unroll
        for (int r = 0; r < 16; r++) {
            float v = oacc[r];
            float sum = __shfl(v, (lane & 32) + 16, 64);
            int prow = (r & 3) + 8 * (r >> 2) + 4 * l5;
            if (l31 < 16)
                o[((size_t)n * 256 + q0i + prow) * CZD + h * 16 + l31] = (bf16_t)(v / sum);
        }
    }
}

// ---------------- small-M latency-tuned MFMA GEMM ----------------
// C[M,N] = epi(A[M,K] @ Bw[N,K]^T + bias). 64x64 tile, BK=64, double-buffered LDS
// with register prefetch. RES: 0 none, 2 += R. ACT: exact GELU. OUTBF: bf16 out.
template <int RES, int ACT, int OUTBF>
__global__ __launch_bounds__(256) void sgemm_kernel(const bf16_t* __restrict__ A,
                                                    const bf16_t* __restrict__ Bw,
                                                    const float* __restrict__ bias,
                                                    const float* __restrict__ R,
                                                    float* __restrict__ C,
                                                    bf16_t* __restrict__ Cb,
                                                    int M, int N, int K) {
    __shared__ bf16_t As[2][64 * 72];
    __shared__ bf16_t Bs[2][64 * 72];
    int tid = threadIdx.x;
    int bm = blockIdx.y * 64, bn = blockIdx.x * 64;
    int lane = tid & 63, wv = tid >> 6;
    int wm = (wv >> 1) * 32, wn = (wv & 1) * 32;
    int lrow = lane & 15, lchunk = lane >> 4;
    int r0 = tid >> 2, c0 = (tid & 3) * 16;

    f32x4 acc[2][2];
#pragma unroll
    for (int i = 0; i < 2; i++)
#pragma unroll
        for (int j = 0; j < 2; j++) acc[i][j] = (f32x4){0.f, 0.f, 0.f, 0.f};

    size_t sa = (size_t)(bm + r0) * K + c0;
    size_t sb = (size_t)(bn + r0) * K + c0;
    uint4 a0 = *(const uint4*)(A + sa);
    uint4 a1 = *(const uint4*)(A + sa + 8);
    uint4 b0 = *(const uint4*)(Bw + sb);
    uint4 b1 = *(const uint4*)(Bw + sb + 8);

    int iters = K >> 6;
    for (int it = 0; it < iters; it++) {
        bf16_t* Aw = &As[it & 1][0];
        bf16_t* Bww = &Bs[it & 1][0];
        *(uint4*)&Aw[r0 * 72 + c0] = a0;
        *(uint4*)&Aw[r0 * 72 + c0 + 8] = a1;
        *(uint4*)&Bww[r0 * 72 + c0] = b0;
        *(uint4*)&Bww[r0 * 72 + c0 + 8] = b1;
        __syncthreads();
        if (it + 1 < iters) {
            size_t oa = sa + (size_t)(it + 1) * 64;
            size_t ob = sb + (size_t)(it + 1) * 64;
            a0 = *(const uint4*)(A + oa);
            a1 = *(const uint4*)(A + oa + 8);
            b0 = *(const uint4*)(Bw + ob);
            b1 = *(const uint4*)(Bw + ob + 8);
        }
#pragma unroll
        for (int ki = 0; ki < 2; ki++) {
            bf16x8 af[2], bfr[2];
#pragma unroll
            for (int f = 0; f < 2; f++) {
                af[f] = *(const bf16x8*)&Aw[(wm + f * 16 + lrow) * 72 + ki * 32 + lchunk * 8];
                bfr[f] = *(const bf16x8*)&Bww[(wn + f * 16 + lrow) * 72 + ki * 32 + lchunk * 8];
            }
#pragma unroll
            for (int fi = 0; fi < 2; fi++)
#pragma unroll
                for (int fj = 0; fj < 2; fj++)
                    acc[fi][fj] = __builtin_amdgcn_mfma_f32_16x16x32_bf16(af[fi], bfr[fj], acc[fi][fj], 0, 0, 0);
        }
        __syncthreads();
    }
#pragma unroll
    for (int fi = 0; fi < 2; fi++) {
#pragma unroll
        for (int i = 0; i < 4; i++) {
            int gm = bm + wm + fi * 16 + lchunk * 4 + i;
            size_t crow = (size_t)gm * N;
#pragma unroll
            for (int fj = 0; fj < 2; fj++) {
                int gn = bn + wn + fj * 16 + lrow;
                float val = acc[fi][fj][i];
                if (bias) val += bias[gn];
                if (ACT == 1) val = 0.5f * val * (1.f + erff(val * 0.70710678118654752f));
                if (RES == 2) val += R[crow + gn];
                if (OUTBF) Cb[crow + gn] = (bf16_t)val;
                else C[crow + gn] = val;
            }
        }
    }
}

// ---------------- large-M bf16 MFMA GEMM (z-track, unchanged from R3) ----------------
template <int APERM, int RES, int ACT, int OUTBF>
__global__ __launch_bounds__(256) void mgemm_kernel(const bf16_t* __restrict__ A,
                                                    const bf16_t* __restrict__ Bw,
                                                    const float* __restrict__ bias,
                                                    const float* __restrict__ R,
                                                    float* __restrict__ C,
                                                    bf16_t* __restrict__ Cb,
                                                    int M, int N, int K) {
    __shared__ bf16_t As[128 * 40];
    __shared__ bf16_t Bs[128 * 40];
    int tid = threadIdx.x;
    int bm = blockIdx.y * 128, bn = blockIdx.x * 128;
    int lane = tid & 63, wvid = tid >> 6;
    int wm = (wvid >> 1) * 64, wn = (wvid & 1) * 64;
    int lrow = lane & 15, lchunk = lane >> 4;

    f32x4 acc[4][4];
#pragma unroll
    for (int i = 0; i < 4; i++)
#pragma unroll
        for (int j = 0; j < 4; j++) acc[i][j] = (f32x4){0.f, 0.f, 0.f, 0.f};

    int r0 = tid >> 2, c0 = tid & 3;
    int ra0 = bm + r0, ra1 = bm + r0 + 64;
    if (APERM) {
        ra0 = ((ra0 & 255) << 8) | (ra0 >> 8);
        ra1 = ((ra1 & 255) << 8) | (ra1 >> 8);
    }
    size_t sa0 = (size_t)ra0 * K, sa1 = (size_t)ra1 * K;
    size_t sb0 = (size_t)(bn + r0) * K, sb1 = (size_t)(bn + r0 + 64) * K;

    for (int k0 = 0; k0 < K; k0 += 32) {
        uint4 va0 = *(const uint4*)(A + sa0 + k0 + c0 * 8);
        uint4 va1 = *(const uint4*)(A + sa1 + k0 + c0 * 8);
        uint4 vb0 = *(const uint4*)(Bw + sb0 + k0 + c0 * 8);
        uint4 vb1 = *(const uint4*)(Bw + sb1 + k0 + c0 * 8);
        __syncthreads();
        *(uint4*)&As[r0 * 40 + c0 * 8] = va0;
        *(uint4*)&As[(r0 + 64) * 40 + c0 * 8] = va1;
        *(uint4*)&Bs[r0 * 40 + c0 * 8] = vb0;
        *(uint4*)&Bs[(r0 + 64) * 40 + c0 * 8] = vb1;
        __syncthreads();
        bf16x8 af[4], bfr[4];
#pragma unroll
        for (int f = 0; f < 4; f++) {
            af[f] = *(const bf16x8*)&As[(wm + f * 16 + lrow) * 40 + lchunk * 8];
            bfr[f] = *(const bf16x8*)&Bs[(wn + f * 16 + lrow) * 40 + lchunk * 8];
        }
#pragma unroll
        for (int fi = 0; fi < 4; fi++)
#pragma unroll
            for (int fj = 0; fj < 4; fj++)
                acc[fi][fj] = __builtin_amdgcn_mfma_f32_16x16x32_bf16(af[fi], bfr[fj], acc[fi][fj], 0, 0, 0);
    }
#pragma unroll
    for (int fi = 0; fi < 4; fi++) {
#pragma unroll
        for (int i = 0; i < 4; i++) {
            int gm = bm + wm + fi * 16 + lchunk * 4 + i;
            size_t crow = (size_t)gm * N;
#pragma unroll
            for (int fj = 0; fj < 4; fj++) {
                int gn = bn + wn + fj * 16 + lrow;
                float val = acc[fi][fj][i];
                if (bias) val += bias[gn];
                if (ACT == 1) val = 0.5f * val * (1.f + erff(val * 0.70710678118654752f));
                if (RES == 1) val += C[crow + gn];
                else if (RES == 2) val += R[crow + gn];
                if (OUTBF) Cb[crow + gn] = (bf16_t)val;
                else C[crow + gn] = val;
            }
        }
    }
}

// ---------------- one-shot weight prep: all transposes/casts/bias-pack ----------------
struct PrepArgs {
    const float *wq, *wk, *wv, *wo, *sffw1, *sffw2, *szi, *szj, *zffw1, *zffw2;
    const float *rinw, *cinw, *routw, *coutw, *bq, *bk, *bv;
    bf16_t *wqkv, *wwo, *wsf1, *wsf2, *wszij, *wzf1, *wzf2;
    bf16_t *wrin, *wcin, *wrout, *wcout;
    float* biasqkv;
};
__device__ inline void dev_trans(const float* in, bf16_t* out, int i, int N, int K) {
    int k = i / N, n = i % N;
    out[(size_t)n * K + k] = (bf16_t)in[i];
}
__global__ void prep_kernel(PrepArgs a) {
    int i = blockIdx.x * 256 + threadIdx.x;
    if (i < 147456) { dev_trans(a.wq, a.wqkv, i, 384, 384); return; }
    i -= 147456;
    if (i < 147456) { dev_trans(a.wk, a.wqkv + 384 * 384, i, 384, 384); return; }
    i -= 147456;
    if (i < 147456) { dev_trans(a.wv, a.wqkv + 768 * 384, i, 384, 384); return; }
    i -= 147456;
    if (i < 147456) { dev_trans(a.wo, a.wwo, i, 384, 384); return; }
    i -= 147456;
    if (i < 589824) { dev_trans(a.sffw1, a.wsf1, i, 1536, 384); return; }
    i -= 589824;
    if (i < 589824) { dev_trans(a.sffw2, a.wsf2, i, 384, 1536); return; }
    i -= 589824;
    if (i < 49152) { dev_trans(a.szi, a.wszij, i, 128, 384); return; }
    i -= 49152;
    if (i < 49152) { dev_trans(a.szj, a.wszij + 128 * 384, i, 128, 384); return; }
    i -= 49152;
    if (i < 65536) { dev_trans(a.zffw1, a.wzf1, i, 512, 128); return; }
    i -= 65536;
    if (i < 65536) { dev_trans(a.zffw2, a.wzf2, i, 128, 512); return; }
    i -= 65536;
    if (i < 49152) { a.wrin[i] = (bf16_t)a.rinw[i]; return; }
    i -= 49152;
    if (i < 49152) { a.wcin[i] = (bf16_t)a.cinw[i]; return; }
    i -= 49152;
    if (i < 16384) { a.wrout[i] = (bf16_t)a.routw[i]; return; }
    i -= 16384;
    if (i < 16384) { a.wcout[i] = (bf16_t)a.coutw[i]; return; }
    i -= 16384;
    if (i < 384) { a.biasqkv[i] = a.bq[i]; return; }
    i -= 384;
    if (i < 384) { a.biasqkv[384 + i] = a.bk[i]; return; }
    i -= 384;
    if (i < 384) { a.biasqkv[768 + i] = a.bv[i]; return; }
}

// ---------------- outer-sum: z[i,j,:] += ab[i,0:128] + ab[j,128:256] ----------------
__global__ void outer_add_kernel(float* __restrict__ z, const float* __restrict__ ab) {
    size_t idx = (size_t)blockIdx.x * blockDim.x + threadIdx.x;
    size_t e = idx * 4;
    int c4 = (int)(e & 127);
    int pair = (int)(e >> 7);
    int i = pair >> 8, j = pair & 255;
    float4 zv = *(float4*)(z + e);
    float4 avv = *(const float4*)(ab + (size_t)i * 256 + c4);
    float4 bvv = *(const float4*)(ab + (size_t)j * 256 + 128 + c4);
    zv.x += avv.x + bvv.x;
    zv.y += avv.y + bvv.y;
    zv.z += avv.z + bvv.z;
    zv.w += avv.w + bvv.w;
    *(float4*)(z + e) = zv;
}

extern "C" void kernel_launch(void* const* d_in, const int* in_sizes, int n_in,
                              void* d_out, int out_size, void* d_ws, size_t ws_size,
                              hipStream_t stream) {
    const float* s_in = (const float*)d_in[0];
    const float* z_in = (const float*)d_in[1];
    const float* sng = (const float*)d_in[3];
    const float* snb = (const float*)d_in[4];
    const float* zng = (const float*)d_in[5];
    const float* znb = (const float*)d_in[6];
    const float* wq = (const float*)d_in[7];
    const float* bq = (const float*)d_in[8];
    const float* wk = (const float*)d_in[9];
    const float* bk = (const float*)d_in[10];
    const float* wv = (const float*)d_in[11];
    const float* bv = (const float*)d_in[12];
    const float* wzb = (const float*)d_in[13];
    const float* bzb = (const float*)d_in[14];
    const float* wo = (const float*)d_in[15];
    const float* bo = (const float*)d_in[16];
    const float* sffw1 = (const float*)d_in[17];
    const float* sffb1 = (const float*)d_in[18];
    const float* sffw2 = (const float*)d_in[19];
    const float* sffb2 = (const float*)d_in[20];
    const float* pzg = (const float*)d_in[21];
    const float* pzb = (const float*)d_in[22];
    const float* rinw = (const float*)d_in[23];
    const float* rinb = (const float*)d_in[24];
    const float* routw = (const float*)d_in[25];
    const float* routb = (const float*)d_in[26];
    const float* cinw = (const float*)d_in[27];
    const float* cinb = (const float*)d_in[28];
    const float* coutw = (const float*)d_in[29];
    const float* coutb = (const float*)d_in[30];
    const float* sziw = (const float*)d_in[31];
    const float* szjw = (const float*)d_in[32];
    const float* zffw1 = (const float*)d_in[33];
    const float* zffb1 = (const float*)d_in[34];
    const float* zffw2 = (const float*)d_in[35];
    const float* zffb2 = (const float*)d_in[36];

    float* ws = (float*)d_ws;
    // big z-track buffers
    bf16_t* qkvbf = (bf16_t*)ws;                   // 65536x384 bf16 (also hbf overlay)
    bf16_t* hbf = (bf16_t*)ws;
    float* obregion = ws + 25165824;               // 4,194,304 floats region
    bf16_t* obbf = (bf16_t*)obregion;              // 65536x128 bf16 (z-track stage)
    bf16_t* znpbf = (bf16_t*)(ws + 29360128);      // 65536x128 bf16
    // s-track transients overlaid in obregion (dead before pattn writes obbf)
    bf16_t* snbf = (bf16_t*)obregion;                      // 256x384
    float* qkv_s = obregion + 49152;                       // 256x1152 fp32
    float* biasb = obregion + 344064;                      // 8x65536
    bf16_t* osbf = (bf16_t*)(obregion + 868352);           // 256x384
    float* s1 = obregion + 917504;                         // 256x384 fp32
    bf16_t* sn2bf = (bf16_t*)(obregion + 1015808);         // 256x384
    bf16_t* hsbf = (bf16_t*)(obregion + 1064960);          // 256x1536
    // persistent weight region
    bf16_t* wrin = (bf16_t*)(ws + 33554432);
    bf16_t* wcin = (bf16_t*)(ws + 33579008);
    bf16_t* wrout = (bf16_t*)(ws + 33603584);
    bf16_t* wcout = (bf16_t*)(ws + 33611776);
    bf16_t* wzf1 = (bf16_t*)(ws + 33619968);
    bf16_t* wzf2 = (bf16_t*)(ws + 33652736);
    bf16_t* wqkv = (bf16_t*)(ws + 33685504);       // 1152x384
    bf16_t* wwo = (bf16_t*)(ws + 33906688);        // 384x384
    bf16_t* wsf1 = (bf16_t*)(ws + 33980416);       // 1536x384
    bf16_t* wsf2 = (bf16_t*)(ws + 34275328);       // 384x1536
    bf16_t* wszij = (bf16_t*)(ws + 34570240);      // 256x384
    float* biasqkv = ws + 34619392;                // 1152
    bf16_t* sn3bf = (bf16_t*)(ws + 34620544);      // 256x384 (lives across pattn)
    float* ab = ws + 34669696;                     // 256x256 fp32

    float* sout = (float*)d_out;
    float* zout = sout + 98304;

    dim3 b256(256);
    dim3 b128(128);

    // --- all weight prep in one dispatch ---
    PrepArgs pa;
    pa.wq = wq; pa.wk = wk; pa.wv = wv; pa.wo = wo;
    pa.sffw1 = sffw1; pa.sffw2 = sffw2; pa.szi = sziw; pa.szj = szjw;
    pa.zffw1 = zffw1; pa.zffw2 = zffw2;
    pa.rinw = rinw; pa.cinw = cinw; pa.routw = routw; pa.coutw = coutw;
    pa.bq = bq; pa.bk = bk; pa.bv = bv;
    pa.wqkv = wqkv; pa.wwo = wwo; pa.wsf1 = wsf1; pa.wsf2 = wsf2; pa.wszij = wszij;
    pa.wzf1 = wzf1; pa.wzf2 = wzf2;
    pa.wrin = wrin; pa.wcin = wcin; pa.wrout = wrout; pa.wcout = wcout;
    pa.biasqkv = biasqkv;
    prep_kernel<<<dim3(8329), b256, 0, stream>>>(pa);

    // --- s attention ---
    ln_kernel<bf16_t><<<dim3(LL), dim3(CSD), 0, stream>>>(s_in, sng, snb, snbf, CSD);
    zbias_kernel<<<dim3(65536), b128, 0, stream>>>(z_in, zng, znb, wzb, bzb, biasb);
    sgemm_kernel<0, 0, 0><<<dim3(18, 4), b256, 0, stream>>>(snbf, wqkv, biasqkv, nullptr, qkv_s, nullptr, 256, 1152, 384);
    sattn_kernel<<<dim3(LL, HNUM), b256, 0, stream>>>(qkv_s, biasb, osbf);
    sgemm_kernel<2, 0, 0><<<dim3(6, 4), b256, 0, stream>>>(osbf, wwo, bo, s_in, s1, nullptr, 256, 384, 384);
    // --- s feedforward ---
    ln_kernel<bf16_t><<<dim3(LL), dim3(CSD), 0, stream>>>(s1, sng, snb, sn2bf, CSD);
    sgemm_kernel<0, 1, 1><<<dim3(24, 4), b256, 0, stream>>>(sn2bf, wsf1, sffb1, nullptr, nullptr, hsbf, 256, 1536, 384);
    sgemm_kernel<2, 0, 0><<<dim3(6, 4), b256, 0, stream>>>(hsbf, wsf2, sffb2, s1, sout, nullptr, 256, 384, 1536);
    // --- outer-sum inputs (before obregion is reused by pattn) ---
    ln_kernel<bf16_t><<<dim3(LL), dim3(CSD), 0, stream>>>(sout, sng, snb, sn3bf, CSD);
    sgemm_kernel<0, 0, 0><<<dim3(4, 4), b256, 0, stream>>>(sn3bf, wszij, nullptr, nullptr, ab, nullptr, 256, 256, 384);
    // --- pair LN ---
    ln_kernel<bf16_t><<<dim3(65536), b128, 0, stream>>>(z_in, pzg, pzb, znpbf, CZD);
    // --- row attention ---
    mgemm_kernel<0, 0, 0, 1><<<dim3(3, 512), b256, 0, stream>>>(znpbf, wrin, rinb, nullptr, nullptr, qkvbf, 65536, 384, CZD);
    pattn_mfma_kernel<<<dim3(256, HNUM), b256, 0, stream>>>(qkvbf, obbf);
    mgemm_kernel<0, 2, 0, 0><<<dim3(1, 512), b256, 0, stream>>>(obbf, wrout, routb, z_in, zout, nullptr, 65536, CZD, CZD);
    // --- col attention ---
    mgemm_kernel<1, 0, 0, 1><<<dim3(3, 512), b256, 0, stream>>>(znpbf, wcin, cinb, nullptr, nullptr, qkvbf, 65536, 384, CZD);
    pattn_mfma_kernel<<<dim3(256, HNUM), b256, 0, stream>>>(qkvbf, obbf);
    mgemm_kernel<1, 1, 0, 0><<<dim3(1, 512), b256, 0, stream>>>(obbf, wcout, coutb, nullptr, zout, nullptr, 65536, CZD, CZD);
    // --- outer sum ---
    outer_add_kernel<<<dim3(8192), b256, 0, stream>>>(zout, ab);
    // --- z feedforward ---
    ln_kernel<bf16_t><<<dim3(65536), b128, 0, stream>>>(zout, zng, znb, znpbf, CZD);
    mgemm_kernel<0, 0, 1, 1><<<dim3(4, 512), b256, 0, stream>>>(znpbf, wzf1, zffb1, nullptr, nullptr, hbf, 65536, 512, CZD);
    mgemm_kernel<0, 1, 0, 0><<<dim3(1, 512), b256, 0, stream>>>(hbf, wzf2, zffb2, nullptr, zout, nullptr, 65536, CZD, 512);
}

// Round 5
// 629.736 us; speedup vs baseline: 2.8490x; 1.1616x over previous
//
#include <hip/hip_runtime.h>
#include <math.h>

#define LL 256
#define CSD 384
#define CZD 128
#define HNUM 8
#define DHS 48
#define DHZ 16

typedef __bf16 bf16_t;
typedef bf16_t bf16x8 __attribute__((ext_vector_type(8)));
typedef float f32x4 __attribute__((ext_vector_type(4)));
typedef float f32x16 __attribute__((ext_vector_type(16)));

// ---------------- LayerNorm (s-track rows, blockDim.x == W) ----------------
template <typename OUT>
__global__ void ln_kernel(const float* __restrict__ x, const float* __restrict__ g,
                          const float* __restrict__ b, OUT* __restrict__ y, int W) {
    size_t row = blockIdx.x;
    int t = threadIdx.x;
    float v = x[row * (size_t)W + t];
    float s = v, s2 = v * v;
#pragma unroll
    for (int o = 32; o > 0; o >>= 1) { s += __shfl_down(s, o); s2 += __shfl_down(s2, o); }
    __shared__ float sh[8], sh2[8];
    int w = t >> 6, nw = W >> 6;
    if ((t & 63) == 0) { sh[w] = s; sh2[w] = s2; }
    __syncthreads();
    if (t == 0) {
        float a = 0, a2 = 0;
        for (int i = 0; i < nw; i++) { a += sh[i]; a2 += sh2[i]; }
        sh[0] = a; sh2[0] = a2;
    }
    __syncthreads();
    float mean = sh[0] / W;
    float var = sh2[0] / W - mean * mean;
    y[row * (size_t)W + t] = (OUT)((v - mean) * rsqrtf(var + 1e-5f) * g[t] + b[t]);
}

// ---------------- fused z-LN: one pass over z -> znp (pz params, bf16) + pair bias ----------
// 8 lanes per 128-wide row; 32 rows per 256-thread block.
__global__ __launch_bounds__(256) void zlnbias_kernel(
        const float* __restrict__ z, const float* __restrict__ zng, const float* __restrict__ znb,
        const float* __restrict__ pzg, const float* __restrict__ pzb,
        const float* __restrict__ wzb, const float* __restrict__ bzb,
        float* __restrict__ bias, bf16_t* __restrict__ znp) {
    __shared__ float swzb[1024];
    int tid = threadIdx.x;
    *(float4*)&swzb[tid * 4] = *(const float4*)&wzb[tid * 4];
    __syncthreads();
    int p = blockIdx.x * 32 + (tid >> 3);
    int g = tid & 7, c0 = g * 16;
    const float* row = z + (size_t)p * 128 + c0;
    float v[16];
#pragma unroll
    for (int i = 0; i < 4; i++) *(float4*)&v[i * 4] = *(const float4*)(row + i * 4);
    float s = 0.f, s2 = 0.f;
#pragma unroll
    for (int c = 0; c < 16; c++) { s += v[c]; s2 += v[c] * v[c]; }
#pragma unroll
    for (int m = 1; m <= 4; m <<= 1) { s += __shfl_xor(s, m); s2 += __shfl_xor(s2, m); }
    float mean = s * 0.0078125f;
    float var = s2 * 0.0078125f - mean * mean;
    float rstd = rsqrtf(var + 1e-5f);
    float zg[16], zb[16], pg[16], pb[16];
#pragma unroll
    for (int i = 0; i < 4; i++) {
        *(float4*)&zg[i * 4] = *(const float4*)(zng + c0 + i * 4);
        *(float4*)&zb[i * 4] = *(const float4*)(znb + c0 + i * 4);
        *(float4*)&pg[i * 4] = *(const float4*)(pzg + c0 + i * 4);
        *(float4*)&pb[i * 4] = *(const float4*)(pzb + c0 + i * 4);
    }
    float pr[8] = {0.f, 0.f, 0.f, 0.f, 0.f, 0.f, 0.f, 0.f};
    bf16_t ob[16];
#pragma unroll
    for (int c = 0; c < 16; c++) {
        float nrm = (v[c] - mean) * rstd;
        ob[c] = (bf16_t)(nrm * pg[c] + pb[c]);
        float zn = nrm * zg[c] + zb[c];
        float4 w0 = *(const float4*)&swzb[(c0 + c) * 8];
        float4 w1 = *(const float4*)&swzb[(c0 + c) * 8 + 4];
        pr[0] += zn * w0.x; pr[1] += zn * w0.y; pr[2] += zn * w0.z; pr[3] += zn * w0.w;
        pr[4] += zn * w1.x; pr[5] += zn * w1.y; pr[6] += zn * w1.z; pr[7] += zn * w1.w;
    }
    bf16_t* orow = znp + (size_t)p * 128 + c0;
    *(uint4*)orow = *(uint4*)&ob[0];
    *(uint4*)(orow + 8) = *(uint4*)&ob[8];
#pragma unroll
    for (int m = 1; m <= 4; m <<= 1)
#pragma unroll
        for (int h = 0; h < 8; h++) pr[h] += __shfl_xor(pr[h], m);
    if (g == 0) {
#pragma unroll
        for (int h = 0; h < 8; h++) bias[(size_t)h * 65536 + p] = pr[h] + bzb[h];
    }
}

// ---------------- fused outer-sum + z-LN: z += outer; write z; LN -> znp bf16 ----------
__global__ __launch_bounds__(256) void outerln_kernel(
        float* __restrict__ z, const float* __restrict__ ab,
        const float* __restrict__ zng, const float* __restrict__ znb,
        bf16_t* __restrict__ znp) {
    int tid = threadIdx.x;
    int p = blockIdx.x * 32 + (tid >> 3);
    int g = tid & 7, c0 = g * 16;
    int i = p >> 8, j = p & 255;
    float* row = z + (size_t)p * 128 + c0;
    float v[16];
#pragma unroll
    for (int q = 0; q < 4; q++) {
        float4 xv = *(const float4*)(row + q * 4);
        float4 av = *(const float4*)(ab + (size_t)i * 256 + c0 + q * 4);
        float4 bv = *(const float4*)(ab + (size_t)j * 256 + 128 + c0 + q * 4);
        v[q * 4 + 0] = xv.x + av.x + bv.x;
        v[q * 4 + 1] = xv.y + av.y + bv.y;
        v[q * 4 + 2] = xv.z + av.z + bv.z;
        v[q * 4 + 3] = xv.w + av.w + bv.w;
        *(float4*)(row + q * 4) = *(float4*)&v[q * 4];
    }
    float s = 0.f, s2 = 0.f;
#pragma unroll
    for (int c = 0; c < 16; c++) { s += v[c]; s2 += v[c] * v[c]; }
#pragma unroll
    for (int m = 1; m <= 4; m <<= 1) { s += __shfl_xor(s, m); s2 += __shfl_xor(s2, m); }
    float mean = s * 0.0078125f;
    float var = s2 * 0.0078125f - mean * mean;
    float rstd = rsqrtf(var + 1e-5f);
    float zg[16], zb[16];
#pragma unroll
    for (int q = 0; q < 4; q++) {
        *(float4*)&zg[q * 4] = *(const float4*)(zng + c0 + q * 4);
        *(float4*)&zb[q * 4] = *(const float4*)(znb + c0 + q * 4);
    }
    bf16_t ob[16];
#pragma unroll
    for (int c = 0; c < 16; c++) ob[c] = (bf16_t)((v[c] - mean) * rstd * zg[c] + zb[c]);
    bf16_t* orow = znp + (size_t)p * 128 + c0;
    *(uint4*)orow = *(uint4*)&ob[0];
    *(uint4*)(orow + 8) = *(uint4*)&ob[8];
}

// ---------------- s-track attention: one block per (query l, head h) ----------------
__global__ void sattn_kernel(const float* __restrict__ qkv, const float* __restrict__ bias,
                             bf16_t* __restrict__ o) {
    int l = blockIdx.x, h = blockIdx.y;
    int m = threadIdx.x;  // 256 keys
    const float* qr = qkv + (size_t)l * 1152 + h * DHS;
    const float* kr = qkv + (size_t)m * 1152 + 384 + h * DHS;
    float acc = 0.f;
#pragma unroll
    for (int d = 0; d < DHS; d++) acc += qr[d] * kr[d];
    acc = acc * 0.14433756729740643f + bias[(size_t)h * 65536 + l * 256 + m];

    __shared__ float attn[256];
    __shared__ float redm[4], reds[4];
    float x = acc;
#pragma unroll
    for (int off = 32; off > 0; off >>= 1) x = fmaxf(x, __shfl_down(x, off));
    if ((m & 63) == 0) redm[m >> 6] = x;
    __syncthreads();
    float mx = fmaxf(fmaxf(redm[0], redm[1]), fmaxf(redm[2], redm[3]));
    float p = __expf(acc - mx);
    float ss = p;
#pragma unroll
    for (int off = 32; off > 0; off >>= 1) ss += __shfl_down(ss, off);
    if ((m & 63) == 0) reds[m >> 6] = ss;
    __syncthreads();
    float sum = reds[0] + reds[1] + reds[2] + reds[3];
    attn[m] = p / sum;
    __syncthreads();
    if (m < DHS) {
        float a = 0.f;
        for (int j = 0; j < 256; j++) a += attn[j] * qkv[(size_t)j * 1152 + 768 + h * DHS + m];
        o[(size_t)l * CSD + h * DHS + m] = (bf16_t)a;
    }
}

// ---------------- MFMA pair attention ----------------
__global__ __launch_bounds__(256) void pattn_mfma_kernel(const bf16_t* __restrict__ qkv,
                                                         bf16_t* __restrict__ o) {
    int n = blockIdx.x, h = blockIdx.y;
    int tid = threadIdx.x;
    __shared__ bf16_t Qs[256 * 24];
    __shared__ bf16_t Ks[256 * 24];
    __shared__ bf16_t Vt[32 * 264];
    __shared__ bf16_t Ps[4][32 * 72];

    {
        const bf16_t* row = qkv + ((size_t)n * 256 + tid) * 384 + h * 16;
        uint4 q0 = *(const uint4*)(row);
        uint4 q1 = *(const uint4*)(row + 8);
        uint4 k0 = *(const uint4*)(row + 128);
        uint4 k1 = *(const uint4*)(row + 136);
        uint4 v0 = *(const uint4*)(row + 256);
        uint4 v1 = *(const uint4*)(row + 264);
        *(uint4*)&Qs[tid * 24] = q0; *(uint4*)&Qs[tid * 24 + 8] = q1;
        *(uint4*)&Ks[tid * 24] = k0; *(uint4*)&Ks[tid * 24 + 8] = k1;
        bf16_t vv[16];
        *(uint4*)&vv[0] = v0; *(uint4*)&vv[8] = v1;
#pragma unroll
        for (int d = 0; d < 16; d++) Vt[d * 264 + tid] = vv[d];
        Vt[16 * 264 + tid] = (bf16_t)1.0f;
    }
    __syncthreads();

    int wv = tid >> 6, lane = tid & 63;
    int l5 = lane >> 5, l31 = lane & 31;
    bf16_t* P = &Ps[wv][0];
    const f32x16 zero16 = {0.f,0.f,0.f,0.f,0.f,0.f,0.f,0.f,0.f,0.f,0.f,0.f,0.f,0.f,0.f,0.f};

    for (int chunk = 0; chunk < 2; chunk++) {
        int q0i = wv * 64 + chunk * 32;
        bf16x8 aq = *(const bf16x8*)&Qs[(q0i + l31) * 24 + l5 * 8];
        f32x16 oacc = zero16;
        for (int kt = 0; kt < 4; kt++) {
#pragma unroll
            for (int ct2 = 0; ct2 < 2; ct2++) {
                int ct = kt * 2 + ct2;
                bf16x8 kb = *(const bf16x8*)&Ks[(ct * 32 + l31) * 24 + l5 * 8];
                f32x16 s = __builtin_amdgcn_mfma_f32_32x32x16_bf16(aq, kb, zero16, 0, 0, 0);
#pragma unroll
                for (int r = 0; r < 16; r++) {
                    float p = __expf(0.25f * s[r]);
                    int prow = (r & 3) + 8 * (r >> 2) + 4 * l5;
                    P[prow * 72 + ct2 * 32 + l31] = (bf16_t)p;
                }
            }
#pragma unroll
            for (int st = 0; st < 4; st++) {
                bf16x8 pa = *(const bf16x8*)&P[l31 * 72 + st * 16 + l5 * 8];
                bf16x8 vb = *(const bf16x8*)&Vt[l31 * 264 + kt * 64 + st * 16 + l5 * 8];
                oacc = __builtin_amdgcn_mfma_f32_32x32x16_bf16(pa, vb, oacc, 0, 0, 0);
            }
        }
#pragma unroll
        for (int r = 0; r < 16; r++) {
            float v = oacc[r];
            float sum = __shfl(v, (lane & 32) + 16, 64);
            int prow = (r & 3) + 8 * (r >> 2) + 4 * l5;
            if (l31 < 16)
                o[((size_t)n * 256 + q0i + prow) * CZD + h * 16 + l31] = (bf16_t)(v / sum);
        }
    }
}

// ---------------- small-M latency-tuned MFMA GEMM ----------------
template <int RES, int ACT, int OUTBF>
__global__ __launch_bounds__(256) void sgemm_kernel(const bf16_t* __restrict__ A,
                                                    const bf16_t* __restrict__ Bw,
                                                    const float* __restrict__ bias,
                                                    const float* __restrict__ R,
                                                    float* __restrict__ C,
                                                    bf16_t* __restrict__ Cb,
                                                    int M, int N, int K) {
    __shared__ bf16_t As[2][64 * 72];
    __shared__ bf16_t Bs[2][64 * 72];
    int tid = threadIdx.x;
    int bm = blockIdx.y * 64, bn = blockIdx.x * 64;
    int lane = tid & 63, wv = tid >> 6;
    int wm = (wv >> 1) * 32, wn = (wv & 1) * 32;
    int lrow = lane & 15, lchunk = lane >> 4;
    int r0 = tid >> 2, c0 = (tid & 3) * 16;

    f32x4 acc[2][2];
#pragma unroll
    for (int i = 0; i < 2; i++)
#pragma unroll
        for (int j = 0; j < 2; j++) acc[i][j] = (f32x4){0.f, 0.f, 0.f, 0.f};

    size_t sa = (size_t)(bm + r0) * K + c0;
    size_t sb = (size_t)(bn + r0) * K + c0;
    uint4 a0 = *(const uint4*)(A + sa);
    uint4 a1 = *(const uint4*)(A + sa + 8);
    uint4 b0 = *(const uint4*)(Bw + sb);
    uint4 b1 = *(const uint4*)(Bw + sb + 8);

    int iters = K >> 6;
    for (int it = 0; it < iters; it++) {
        bf16_t* Aw = &As[it & 1][0];
        bf16_t* Bww = &Bs[it & 1][0];
        *(uint4*)&Aw[r0 * 72 + c0] = a0;
        *(uint4*)&Aw[r0 * 72 + c0 + 8] = a1;
        *(uint4*)&Bww[r0 * 72 + c0] = b0;
        *(uint4*)&Bww[r0 * 72 + c0 + 8] = b1;
        __syncthreads();
        if (it + 1 < iters) {
            size_t oa = sa + (size_t)(it + 1) * 64;
            size_t ob = sb + (size_t)(it + 1) * 64;
            a0 = *(const uint4*)(A + oa);
            a1 = *(const uint4*)(A + oa + 8);
            b0 = *(const uint4*)(Bw + ob);
            b1 = *(const uint4*)(Bw + ob + 8);
        }
#pragma unroll
        for (int ki = 0; ki < 2; ki++) {
            bf16x8 af[2], bfr[2];
#pragma unroll
            for (int f = 0; f < 2; f++) {
                af[f] = *(const bf16x8*)&Aw[(wm + f * 16 + lrow) * 72 + ki * 32 + lchunk * 8];
                bfr[f] = *(const bf16x8*)&Bww[(wn + f * 16 + lrow) * 72 + ki * 32 + lchunk * 8];
            }
#pragma unroll
            for (int fi = 0; fi < 2; fi++)
#pragma unroll
                for (int fj = 0; fj < 2; fj++)
                    acc[fi][fj] = __builtin_amdgcn_mfma_f32_16x16x32_bf16(af[fi], bfr[fj], acc[fi][fj], 0, 0, 0);
        }
        __syncthreads();
    }
#pragma unroll
    for (int fi = 0; fi < 2; fi++) {
#pragma unroll
        for (int i = 0; i < 4; i++) {
            int gm = bm + wm + fi * 16 + lchunk * 4 + i;
            size_t crow = (size_t)gm * N;
#pragma unroll
            for (int fj = 0; fj < 2; fj++) {
                int gn = bn + wn + fj * 16 + lrow;
                float val = acc[fi][fj][i];
                if (bias) val += bias[gn];
                if (ACT == 1) val = 0.5f * val * (1.f + erff(val * 0.70710678118654752f));
                if (RES == 2) val += R[crow + gn];
                if (OUTBF) Cb[crow + gn] = (bf16_t)val;
                else C[crow + gn] = val;
            }
        }
    }
}

// ---------------- large-M bf16 MFMA GEMM (z-track) ----------------
template <int APERM, int RES, int ACT, int OUTBF>
__global__ __launch_bounds__(256) void mgemm_kernel(const bf16_t* __restrict__ A,
                                                    const bf16_t* __restrict__ Bw,
                                                    const float* __restrict__ bias,
                                                    const float* __restrict__ R,
                                                    float* __restrict__ C,
                                                    bf16_t* __restrict__ Cb,
                                                    int M, int N, int K) {
    __shared__ bf16_t As[128 * 40];
    __shared__ bf16_t Bs[128 * 40];
    int tid = threadIdx.x;
    int bm = blockIdx.y * 128, bn = blockIdx.x * 128;
    int lane = tid & 63, wvid = tid >> 6;
    int wm = (wvid >> 1) * 64, wn = (wvid & 1) * 64;
    int lrow = lane & 15, lchunk = lane >> 4;

    f32x4 acc[4][4];
#pragma unroll
    for (int i = 0; i < 4; i++)
#pragma unroll
        for (int j = 0; j < 4; j++) acc[i][j] = (f32x4){0.f, 0.f, 0.f, 0.f};

    int r0 = tid >> 2, c0 = tid & 3;
    int ra0 = bm + r0, ra1 = bm + r0 + 64;
    if (APERM) {
        ra0 = ((ra0 & 255) << 8) | (ra0 >> 8);
        ra1 = ((ra1 & 255) << 8) | (ra1 >> 8);
    }
    size_t sa0 = (size_t)ra0 * K, sa1 = (size_t)ra1 * K;
    size_t sb0 = (size_t)(bn + r0) * K, sb1 = (size_t)(bn + r0 + 64) * K;

    for (int k0 = 0; k0 < K; k0 += 32) {
        uint4 va0 = *(const uint4*)(A + sa0 + k0 + c0 * 8);
        uint4 va1 = *(const uint4*)(A + sa1 + k0 + c0 * 8);
        uint4 vb0 = *(const uint4*)(Bw + sb0 + k0 + c0 * 8);
        uint4 vb1 = *(const uint4*)(Bw + sb1 + k0 + c0 * 8);
        __syncthreads();
        *(uint4*)&As[r0 * 40 + c0 * 8] = va0;
        *(uint4*)&As[(r0 + 64) * 40 + c0 * 8] = va1;
        *(uint4*)&Bs[r0 * 40 + c0 * 8] = vb0;
        *(uint4*)&Bs[(r0 + 64) * 40 + c0 * 8] = vb1;
        __syncthreads();
        bf16x8 af[4], bfr[4];
#pragma unroll
        for (int f = 0; f < 4; f++) {
            af[f] = *(const bf16x8*)&As[(wm + f * 16 + lrow) * 40 + lchunk * 8];
            bfr[f] = *(const bf16x8*)&Bs[(wn + f * 16 + lrow) * 40 + lchunk * 8];
        }
#pragma unroll
        for (int fi = 0; fi < 4; fi++)
#pragma unroll
            for (int fj = 0; fj < 4; fj++)
                acc[fi][fj] = __builtin_amdgcn_mfma_f32_16x16x32_bf16(af[fi], bfr[fj], acc[fi][fj], 0, 0, 0);
    }
#pragma unroll
    for (int fi = 0; fi < 4; fi++) {
#pragma unroll
        for (int i = 0; i < 4; i++) {
            int gm = bm + wm + fi * 16 + lchunk * 4 + i;
            size_t crow = (size_t)gm * N;
#pragma unroll
            for (int fj = 0; fj < 4; fj++) {
                int gn = bn + wn + fj * 16 + lrow;
                float val = acc[fi][fj][i];
                if (bias) val += bias[gn];
                if (ACT == 1) val = 0.5f * val * (1.f + erff(val * 0.70710678118654752f));
                if (RES == 1) val += C[crow + gn];
                else if (RES == 2) val += R[crow + gn];
                if (OUTBF) Cb[crow + gn] = (bf16_t)val;
                else C[crow + gn] = val;
            }
        }
    }
}

// ---------------- one-shot weight prep ----------------
struct PrepArgs {
    const float *wq, *wk, *wv, *wo, *sffw1, *sffw2, *szi, *szj, *zffw1, *zffw2;
    const float *rinw, *cinw, *routw, *coutw, *bq, *bk, *bv;
    bf16_t *wqkv, *wwo, *wsf1, *wsf2, *wszij, *wzf1, *wzf2;
    bf16_t *wrin, *wcin, *wrout, *wcout;
    float* biasqkv;
};
__device__ inline void dev_trans(const float* in, bf16_t* out, int i, int N, int K) {
    int k = i / N, n = i % N;
    out[(size_t)n * K + k] = (bf16_t)in[i];
}
__global__ void prep_kernel(PrepArgs a) {
    int i = blockIdx.x * 256 + threadIdx.x;
    if (i < 147456) { dev_trans(a.wq, a.wqkv, i, 384, 384); return; }
    i -= 147456;
    if (i < 147456) { dev_trans(a.wk, a.wqkv + 384 * 384, i, 384, 384); return; }
    i -= 147456;
    if (i < 147456) { dev_trans(a.wv, a.wqkv + 768 * 384, i, 384, 384); return; }
    i -= 147456;
    if (i < 147456) { dev_trans(a.wo, a.wwo, i, 384, 384); return; }
    i -= 147456;
    if (i < 589824) { dev_trans(a.sffw1, a.wsf1, i, 1536, 384); return; }
    i -= 589824;
    if (i < 589824) { dev_trans(a.sffw2, a.wsf2, i, 384, 1536); return; }
    i -= 589824;
    if (i < 49152) { dev_trans(a.szi, a.wszij, i, 128, 384); return; }
    i -= 49152;
    if (i < 49152) { dev_trans(a.szj, a.wszij + 128 * 384, i, 128, 384); return; }
    i -= 49152;
    if (i < 65536) { dev_trans(a.zffw1, a.wzf1, i, 512, 128); return; }
    i -= 65536;
    if (i < 65536) { dev_trans(a.zffw2, a.wzf2, i, 128, 512); return; }
    i -= 65536;
    if (i < 49152) { a.wrin[i] = (bf16_t)a.rinw[i]; return; }
    i -= 49152;
    if (i < 49152) { a.wcin[i] = (bf16_t)a.cinw[i]; return; }
    i -= 49152;
    if (i < 16384) { a.wrout[i] = (bf16_t)a.routw[i]; return; }
    i -= 16384;
    if (i < 16384) { a.wcout[i] = (bf16_t)a.coutw[i]; return; }
    i -= 16384;
    if (i < 384) { a.biasqkv[i] = a.bq[i]; return; }
    i -= 384;
    if (i < 384) { a.biasqkv[384 + i] = a.bk[i]; return; }
    i -= 384;
    if (i < 384) { a.biasqkv[768 + i] = a.bv[i]; return; }
}

extern "C" void kernel_launch(void* const* d_in, const int* in_sizes, int n_in,
                              void* d_out, int out_size, void* d_ws, size_t ws_size,
                              hipStream_t stream) {
    const float* s_in = (const float*)d_in[0];
    const float* z_in = (const float*)d_in[1];
    const float* sng = (const float*)d_in[3];
    const float* snb = (const float*)d_in[4];
    const float* zng = (const float*)d_in[5];
    const float* znb = (const float*)d_in[6];
    const float* wq = (const float*)d_in[7];
    const float* bq = (const float*)d_in[8];
    const float* wk = (const float*)d_in[9];
    const float* bk = (const float*)d_in[10];
    const float* wv = (const float*)d_in[11];
    const float* bv = (const float*)d_in[12];
    const float* wzb = (const float*)d_in[13];
    const float* bzb = (const float*)d_in[14];
    const float* wo = (const float*)d_in[15];
    const float* bo = (const float*)d_in[16];
    const float* sffw1 = (const float*)d_in[17];
    const float* sffb1 = (const float*)d_in[18];
    const float* sffw2 = (const float*)d_in[19];
    const float* sffb2 = (const float*)d_in[20];
    const float* pzg = (const float*)d_in[21];
    const float* pzb = (const float*)d_in[22];
    const float* rinw = (const float*)d_in[23];
    const float* rinb = (const float*)d_in[24];
    const float* routw = (const float*)d_in[25];
    const float* routb = (const float*)d_in[26];
    const float* cinw = (const float*)d_in[27];
    const float* cinb = (const float*)d_in[28];
    const float* coutw = (const float*)d_in[29];
    const float* coutb = (const float*)d_in[30];
    const float* sziw = (const float*)d_in[31];
    const float* szjw = (const float*)d_in[32];
    const float* zffw1 = (const float*)d_in[33];
    const float* zffb1 = (const float*)d_in[34];
    const float* zffw2 = (const float*)d_in[35];
    const float* zffb2 = (const float*)d_in[36];

    float* ws = (float*)d_ws;
    bf16_t* qkvbf = (bf16_t*)ws;                   // 65536x384 bf16 (also hbf overlay)
    bf16_t* hbf = (bf16_t*)ws;
    float* obregion = ws + 25165824;               // 4,194,304 floats region
    bf16_t* obbf = (bf16_t*)obregion;              // 65536x128 bf16 (z-track stage)
    bf16_t* znpbf = (bf16_t*)(ws + 29360128);      // 65536x128 bf16
    // s-track transients overlaid in obregion (dead before pattn writes obbf)
    bf16_t* snbf = (bf16_t*)obregion;                      // 256x384
    float* qkv_s = obregion + 49152;                       // 256x1152 fp32
    float* biasb = obregion + 344064;                      // 8x65536
    bf16_t* osbf = (bf16_t*)(obregion + 868352);           // 256x384
    float* s1 = obregion + 917504;                         // 256x384 fp32
    bf16_t* sn2bf = (bf16_t*)(obregion + 1015808);         // 256x384
    bf16_t* hsbf = (bf16_t*)(obregion + 1064960);          // 256x1536
    // persistent weight region
    bf16_t* wrin = (bf16_t*)(ws + 33554432);
    bf16_t* wcin = (bf16_t*)(ws + 33579008);
    bf16_t* wrout = (bf16_t*)(ws + 33603584);
    bf16_t* wcout = (bf16_t*)(ws + 33611776);
    bf16_t* wzf1 = (bf16_t*)(ws + 33619968);
    bf16_t* wzf2 = (bf16_t*)(ws + 33652736);
    bf16_t* wqkv = (bf16_t*)(ws + 33685504);       // 1152x384
    bf16_t* wwo = (bf16_t*)(ws + 33906688);        // 384x384
    bf16_t* wsf1 = (bf16_t*)(ws + 33980416);       // 1536x384
    bf16_t* wsf2 = (bf16_t*)(ws + 34275328);       // 384x1536
    bf16_t* wszij = (bf16_t*)(ws + 34570240);      // 256x384
    float* biasqkv = ws + 34619392;                // 1152
    bf16_t* sn3bf = (bf16_t*)(ws + 34620544);      // 256x384 (lives across pattn)
    float* ab = ws + 34669696;                     // 256x256 fp32

    float* sout = (float*)d_out;
    float* zout = sout + 98304;

    dim3 b256(256);

    // --- all weight prep in one dispatch ---
    PrepArgs pa;
    pa.wq = wq; pa.wk = wk; pa.wv = wv; pa.wo = wo;
    pa.sffw1 = sffw1; pa.sffw2 = sffw2; pa.szi = sziw; pa.szj = szjw;
    pa.zffw1 = zffw1; pa.zffw2 = zffw2;
    pa.rinw = rinw; pa.cinw = cinw; pa.routw = routw; pa.coutw = coutw;
    pa.bq = bq; pa.bk = bk; pa.bv = bv;
    pa.wqkv = wqkv; pa.wwo = wwo; pa.wsf1 = wsf1; pa.wsf2 = wsf2; pa.wszij = wszij;
    pa.wzf1 = wzf1; pa.wzf2 = wzf2;
    pa.wrin = wrin; pa.wcin = wcin; pa.wrout = wrout; pa.wcout = wcout;
    pa.biasqkv = biasqkv;
    prep_kernel<<<dim3(8329), b256, 0, stream>>>(pa);

    // --- fused z LN: znp (bf16) + pair bias, one pass over z ---
    zlnbias_kernel<<<dim3(2048), b256, 0, stream>>>(z_in, zng, znb, pzg, pzb, wzb, bzb, biasb, znpbf);

    // --- s attention ---
    ln_kernel<bf16_t><<<dim3(LL), dim3(CSD), 0, stream>>>(s_in, sng, snb, snbf, CSD);
    sgemm_kernel<0, 0, 0><<<dim3(18, 4), b256, 0, stream>>>(snbf, wqkv, biasqkv, nullptr, qkv_s, nullptr, 256, 1152, 384);
    sattn_kernel<<<dim3(LL, HNUM), b256, 0, stream>>>(qkv_s, biasb, osbf);
    sgemm_kernel<2, 0, 0><<<dim3(6, 4), b256, 0, stream>>>(osbf, wwo, bo, s_in, s1, nullptr, 256, 384, 384);
    // --- s feedforward ---
    ln_kernel<bf16_t><<<dim3(LL), dim3(CSD), 0, stream>>>(s1, sng, snb, sn2bf, CSD);
    sgemm_kernel<0, 1, 1><<<dim3(24, 4), b256, 0, stream>>>(sn2bf, wsf1, sffb1, nullptr, nullptr, hsbf, 256, 1536, 384);
    sgemm_kernel<2, 0, 0><<<dim3(6, 4), b256, 0, stream>>>(hsbf, wsf2, sffb2, s1, sout, nullptr, 256, 384, 1536);
    // --- outer-sum inputs ---
    ln_kernel<bf16_t><<<dim3(LL), dim3(CSD), 0, stream>>>(sout, sng, snb, sn3bf, CSD);
    sgemm_kernel<0, 0, 0><<<dim3(4, 4), b256, 0, stream>>>(sn3bf, wszij, nullptr, nullptr, ab, nullptr, 256, 256, 384);
    // --- row attention ---
    mgemm_kernel<0, 0, 0, 1><<<dim3(3, 512), b256, 0, stream>>>(znpbf, wrin, rinb, nullptr, nullptr, qkvbf, 65536, 384, CZD);
    pattn_mfma_kernel<<<dim3(256, HNUM), b256, 0, stream>>>(qkvbf, obbf);
    mgemm_kernel<0, 2, 0, 0><<<dim3(1, 512), b256, 0, stream>>>(obbf, wrout, routb, z_in, zout, nullptr, 65536, CZD, CZD);
    // --- col attention ---
    mgemm_kernel<1, 0, 0, 1><<<dim3(3, 512), b256, 0, stream>>>(znpbf, wcin, cinb, nullptr, nullptr, qkvbf, 65536, 384, CZD);
    pattn_mfma_kernel<<<dim3(256, HNUM), b256, 0, stream>>>(qkvbf, obbf);
    mgemm_kernel<1, 1, 0, 0><<<dim3(1, 512), b256, 0, stream>>>(obbf, wcout, coutb, nullptr, zout, nullptr, 65536, CZD, CZD);
    // --- fused outer sum + z LN (znf -> znpbf) ---
    outerln_kernel<<<dim3(2048), b256, 0, stream>>>(zout, ab, zng, znb, znpbf);
    // --- z feedforward ---
    mgemm_kernel<0, 0, 1, 1><<<dim3(4, 512), b256, 0, stream>>>(znpbf, wzf1, zffb1, nullptr, nullptr, hbf, 65536, 512, CZD);
    mgemm_kernel<0, 1, 0, 0><<<dim3(1, 512), b256, 0, stream>>>(hbf, wzf2, zffb2, nullptr, zout, nullptr, 65536, CZD, 512);
}

// Round 6
// 591.328 us; speedup vs baseline: 3.0341x; 1.0650x over previous
//
#include <hip/hip_runtime.h>
#include <math.h>

#define LL 256
#define CSD 384
#define CZD 128
#define HNUM 8
#define DHS 48
#define DHZ 16

typedef __bf16 bf16_t;
typedef bf16_t bf16x8 __attribute__((ext_vector_type(8)));
typedef float f32x4 __attribute__((ext_vector_type(4)));
typedef float f32x16 __attribute__((ext_vector_type(16)));

// ---------------- LayerNorm (s-track rows, blockDim.x == W) ----------------
template <typename OUT>
__global__ void ln_kernel(const float* __restrict__ x, const float* __restrict__ g,
                          const float* __restrict__ b, OUT* __restrict__ y, int W) {
    size_t row = blockIdx.x;
    int t = threadIdx.x;
    float v = x[row * (size_t)W + t];
    float s = v, s2 = v * v;
#pragma unroll
    for (int o = 32; o > 0; o >>= 1) { s += __shfl_down(s, o); s2 += __shfl_down(s2, o); }
    __shared__ float sh[8], sh2[8];
    int w = t >> 6, nw = W >> 6;
    if ((t & 63) == 0) { sh[w] = s; sh2[w] = s2; }
    __syncthreads();
    if (t == 0) {
        float a = 0, a2 = 0;
        for (int i = 0; i < nw; i++) { a += sh[i]; a2 += sh2[i]; }
        sh[0] = a; sh2[0] = a2;
    }
    __syncthreads();
    float mean = sh[0] / W;
    float var = sh2[0] / W - mean * mean;
    y[row * (size_t)W + t] = (OUT)((v - mean) * rsqrtf(var + 1e-5f) * g[t] + b[t]);
}

// ---------------- fused z-LN: one pass over z -> znp (pz params, bf16) + pair bias ----------
__global__ __launch_bounds__(256) void zlnbias_kernel(
        const float* __restrict__ z, const float* __restrict__ zng, const float* __restrict__ znb,
        const float* __restrict__ pzg, const float* __restrict__ pzb,
        const float* __restrict__ wzb, const float* __restrict__ bzb,
        float* __restrict__ bias, bf16_t* __restrict__ znp) {
    __shared__ float swzb[1024];
    int tid = threadIdx.x;
    *(float4*)&swzb[tid * 4] = *(const float4*)&wzb[tid * 4];
    __syncthreads();
    int p = blockIdx.x * 32 + (tid >> 3);
    int g = tid & 7, c0 = g * 16;
    const float* row = z + (size_t)p * 128 + c0;
    float v[16];
#pragma unroll
    for (int i = 0; i < 4; i++) *(float4*)&v[i * 4] = *(const float4*)(row + i * 4);
    float s = 0.f, s2 = 0.f;
#pragma unroll
    for (int c = 0; c < 16; c++) { s += v[c]; s2 += v[c] * v[c]; }
#pragma unroll
    for (int m = 1; m <= 4; m <<= 1) { s += __shfl_xor(s, m); s2 += __shfl_xor(s2, m); }
    float mean = s * 0.0078125f;
    float var = s2 * 0.0078125f - mean * mean;
    float rstd = rsqrtf(var + 1e-5f);
    float zg[16], zb[16], pg[16], pb[16];
#pragma unroll
    for (int i = 0; i < 4; i++) {
        *(float4*)&zg[i * 4] = *(const float4*)(zng + c0 + i * 4);
        *(float4*)&zb[i * 4] = *(const float4*)(znb + c0 + i * 4);
        *(float4*)&pg[i * 4] = *(const float4*)(pzg + c0 + i * 4);
        *(float4*)&pb[i * 4] = *(const float4*)(pzb + c0 + i * 4);
    }
    float pr[8] = {0.f, 0.f, 0.f, 0.f, 0.f, 0.f, 0.f, 0.f};
    bf16_t ob[16];
#pragma unroll
    for (int c = 0; c < 16; c++) {
        float nrm = (v[c] - mean) * rstd;
        ob[c] = (bf16_t)(nrm * pg[c] + pb[c]);
        float zn = nrm * zg[c] + zb[c];
        float4 w0 = *(const float4*)&swzb[(c0 + c) * 8];
        float4 w1 = *(const float4*)&swzb[(c0 + c) * 8 + 4];
        pr[0] += zn * w0.x; pr[1] += zn * w0.y; pr[2] += zn * w0.z; pr[3] += zn * w0.w;
        pr[4] += zn * w1.x; pr[5] += zn * w1.y; pr[6] += zn * w1.z; pr[7] += zn * w1.w;
    }
    bf16_t* orow = znp + (size_t)p * 128 + c0;
    *(uint4*)orow = *(uint4*)&ob[0];
    *(uint4*)(orow + 8) = *(uint4*)&ob[8];
#pragma unroll
    for (int m = 1; m <= 4; m <<= 1)
#pragma unroll
        for (int h = 0; h < 8; h++) pr[h] += __shfl_xor(pr[h], m);
    if (g == 0) {
#pragma unroll
        for (int h = 0; h < 8; h++) bias[(size_t)h * 65536 + p] = pr[h] + bzb[h];
    }
}

// ---------------- s-track attention ----------------
__global__ void sattn_kernel(const float* __restrict__ qkv, const float* __restrict__ bias,
                             bf16_t* __restrict__ o) {
    int l = blockIdx.x, h = blockIdx.y;
    int m = threadIdx.x;
    const float* qr = qkv + (size_t)l * 1152 + h * DHS;
    const float* kr = qkv + (size_t)m * 1152 + 384 + h * DHS;
    float acc = 0.f;
#pragma unroll
    for (int d = 0; d < DHS; d++) acc += qr[d] * kr[d];
    acc = acc * 0.14433756729740643f + bias[(size_t)h * 65536 + l * 256 + m];

    __shared__ float attn[256];
    __shared__ float redm[4], reds[4];
    float x = acc;
#pragma unroll
    for (int off = 32; off > 0; off >>= 1) x = fmaxf(x, __shfl_down(x, off));
    if ((m & 63) == 0) redm[m >> 6] = x;
    __syncthreads();
    float mx = fmaxf(fmaxf(redm[0], redm[1]), fmaxf(redm[2], redm[3]));
    float p = __expf(acc - mx);
    float ss = p;
#pragma unroll
    for (int off = 32; off > 0; off >>= 1) ss += __shfl_down(ss, off);
    if ((m & 63) == 0) reds[m >> 6] = ss;
    __syncthreads();
    float sum = reds[0] + reds[1] + reds[2] + reds[3];
    attn[m] = p / sum;
    __syncthreads();
    if (m < DHS) {
        float a = 0.f;
        for (int j = 0; j < 256; j++) a += attn[j] * qkv[(size_t)j * 1152 + 768 + h * DHS + m];
        o[(size_t)l * CSD + h * DHS + m] = (bf16_t)a;
    }
}

// ---------------- MFMA pair attention ----------------
__global__ __launch_bounds__(256) void pattn_mfma_kernel(const bf16_t* __restrict__ qkv,
                                                         bf16_t* __restrict__ o) {
    int n = blockIdx.x, h = blockIdx.y;
    int tid = threadIdx.x;
    __shared__ bf16_t Qs[256 * 24];
    __shared__ bf16_t Ks[256 * 24];
    __shared__ bf16_t Vt[32 * 264];
    __shared__ bf16_t Ps[4][32 * 72];

    {
        const bf16_t* row = qkv + ((size_t)n * 256 + tid) * 384 + h * 16;
        uint4 q0 = *(const uint4*)(row);
        uint4 q1 = *(const uint4*)(row + 8);
        uint4 k0 = *(const uint4*)(row + 128);
        uint4 k1 = *(const uint4*)(row + 136);
        uint4 v0 = *(const uint4*)(row + 256);
        uint4 v1 = *(const uint4*)(row + 264);
        *(uint4*)&Qs[tid * 24] = q0; *(uint4*)&Qs[tid * 24 + 8] = q1;
        *(uint4*)&Ks[tid * 24] = k0; *(uint4*)&Ks[tid * 24 + 8] = k1;
        bf16_t vv[16];
        *(uint4*)&vv[0] = v0; *(uint4*)&vv[8] = v1;
#pragma unroll
        for (int d = 0; d < 16; d++) Vt[d * 264 + tid] = vv[d];
        Vt[16 * 264 + tid] = (bf16_t)1.0f;
    }
    __syncthreads();

    int wv = tid >> 6, lane = tid & 63;
    int l5 = lane >> 5, l31 = lane & 31;
    bf16_t* P = &Ps[wv][0];
    const f32x16 zero16 = {0.f,0.f,0.f,0.f,0.f,0.f,0.f,0.f,0.f,0.f,0.f,0.f,0.f,0.f,0.f,0.f};

    for (int chunk = 0; chunk < 2; chunk++) {
        int q0i = wv * 64 + chunk * 32;
        bf16x8 aq = *(const bf16x8*)&Qs[(q0i + l31) * 24 + l5 * 8];
        f32x16 oacc = zero16;
        for (int kt = 0; kt < 4; kt++) {
#pragma unroll
            for (int ct2 = 0; ct2 < 2; ct2++) {
                int ct = kt * 2 + ct2;
                bf16x8 kb = *(const bf16x8*)&Ks[(ct * 32 + l31) * 24 + l5 * 8];
                f32x16 s = __builtin_amdgcn_mfma_f32_32x32x16_bf16(aq, kb, zero16, 0, 0, 0);
#pragma unroll
                for (int r = 0; r < 16; r++) {
                    float p = __expf(0.25f * s[r]);
                    int prow = (r & 3) + 8 * (r >> 2) + 4 * l5;
                    P[prow * 72 + ct2 * 32 + l31] = (bf16_t)p;
                }
            }
#pragma unroll
            for (int st = 0; st < 4; st++) {
                bf16x8 pa = *(const bf16x8*)&P[l31 * 72 + st * 16 + l5 * 8];
                bf16x8 vb = *(const bf16x8*)&Vt[l31 * 264 + kt * 64 + st * 16 + l5 * 8];
                oacc = __builtin_amdgcn_mfma_f32_32x32x16_bf16(pa, vb, oacc, 0, 0, 0);
            }
        }
#pragma unroll
        for (int r = 0; r < 16; r++) {
            float v = oacc[r];
            float sum = __shfl(v, (lane & 32) + 16, 64);
            int prow = (r & 3) + 8 * (r >> 2) + 4 * l5;
            if (l31 < 16)
                o[((size_t)n * 256 + q0i + prow) * CZD + h * 16 + l31] = (bf16_t)(v / sum);
        }
    }
}

// ---------------- small-M latency-tuned MFMA GEMM ----------------
template <int RES, int ACT, int OUTBF>
__global__ __launch_bounds__(256) void sgemm_kernel(const bf16_t* __restrict__ A,
                                                    const bf16_t* __restrict__ Bw,
                                                    const float* __restrict__ bias,
                                                    const float* __restrict__ R,
                                                    float* __restrict__ C,
                                                    bf16_t* __restrict__ Cb,
                                                    int M, int N, int K) {
    __shared__ bf16_t As[2][64 * 72];
    __shared__ bf16_t Bs[2][64 * 72];
    int tid = threadIdx.x;
    int bm = blockIdx.y * 64, bn = blockIdx.x * 64;
    int lane = tid & 63, wv = tid >> 6;
    int wm = (wv >> 1) * 32, wn = (wv & 1) * 32;
    int lrow = lane & 15, lchunk = lane >> 4;
    int r0 = tid >> 2, c0 = (tid & 3) * 16;

    f32x4 acc[2][2];
#pragma unroll
    for (int i = 0; i < 2; i++)
#pragma unroll
        for (int j = 0; j < 2; j++) acc[i][j] = (f32x4){0.f, 0.f, 0.f, 0.f};

    size_t sa = (size_t)(bm + r0) * K + c0;
    size_t sb = (size_t)(bn + r0) * K + c0;
    uint4 a0 = *(const uint4*)(A + sa);
    uint4 a1 = *(const uint4*)(A + sa + 8);
    uint4 b0 = *(const uint4*)(Bw + sb);
    uint4 b1 = *(const uint4*)(Bw + sb + 8);

    int iters = K >> 6;
    for (int it = 0; it < iters; it++) {
        bf16_t* Aw = &As[it & 1][0];
        bf16_t* Bww = &Bs[it & 1][0];
        *(uint4*)&Aw[r0 * 72 + c0] = a0;
        *(uint4*)&Aw[r0 * 72 + c0 + 8] = a1;
        *(uint4*)&Bww[r0 * 72 + c0] = b0;
        *(uint4*)&Bww[r0 * 72 + c0 + 8] = b1;
        __syncthreads();
        if (it + 1 < iters) {
            size_t oa = sa + (size_t)(it + 1) * 64;
            size_t ob = sb + (size_t)(it + 1) * 64;
            a0 = *(const uint4*)(A + oa);
            a1 = *(const uint4*)(A + oa + 8);
            b0 = *(const uint4*)(Bw + ob);
            b1 = *(const uint4*)(Bw + ob + 8);
        }
#pragma unroll
        for (int ki = 0; ki < 2; ki++) {
            bf16x8 af[2], bfr[2];
#pragma unroll
            for (int f = 0; f < 2; f++) {
                af[f] = *(const bf16x8*)&Aw[(wm + f * 16 + lrow) * 72 + ki * 32 + lchunk * 8];
                bfr[f] = *(const bf16x8*)&Bww[(wn + f * 16 + lrow) * 72 + ki * 32 + lchunk * 8];
            }
#pragma unroll
            for (int fi = 0; fi < 2; fi++)
#pragma unroll
                for (int fj = 0; fj < 2; fj++)
                    acc[fi][fj] = __builtin_amdgcn_mfma_f32_16x16x32_bf16(af[fi], bfr[fj], acc[fi][fj], 0, 0, 0);
        }
        __syncthreads();
    }
#pragma unroll
    for (int fi = 0; fi < 2; fi++) {
#pragma unroll
        for (int i = 0; i < 4; i++) {
            int gm = bm + wm + fi * 16 + lchunk * 4 + i;
            size_t crow = (size_t)gm * N;
#pragma unroll
            for (int fj = 0; fj < 2; fj++) {
                int gn = bn + wn + fj * 16 + lrow;
                float val = acc[fi][fj][i];
                if (bias) val += bias[gn];
                if (ACT == 1) val = 0.5f * val * (1.f + erff(val * 0.70710678118654752f));
                if (RES == 2) val += R[crow + gn];
                if (OUTBF) Cb[crow + gn] = (bf16_t)val;
                else C[crow + gn] = val;
            }
        }
    }
}

// ---------------- large-M bf16 MFMA GEMM (rowin/colin/rowout) ----------------
template <int APERM, int RES, int ACT, int OUTBF>
__global__ __launch_bounds__(256) void mgemm_kernel(const bf16_t* __restrict__ A,
                                                    const bf16_t* __restrict__ Bw,
                                                    const float* __restrict__ bias,
                                                    const float* __restrict__ R,
                                                    float* __restrict__ C,
                                                    bf16_t* __restrict__ Cb,
                                                    int M, int N, int K) {
    __shared__ bf16_t As[128 * 40];
    __shared__ bf16_t Bs[128 * 40];
    int tid = threadIdx.x;
    int bm = blockIdx.y * 128, bn = blockIdx.x * 128;
    int lane = tid & 63, wvid = tid >> 6;
    int wm = (wvid >> 1) * 64, wn = (wvid & 1) * 64;
    int lrow = lane & 15, lchunk = lane >> 4;

    f32x4 acc[4][4];
#pragma unroll
    for (int i = 0; i < 4; i++)
#pragma unroll
        for (int j = 0; j < 4; j++) acc[i][j] = (f32x4){0.f, 0.f, 0.f, 0.f};

    int r0 = tid >> 2, c0 = tid & 3;
    int ra0 = bm + r0, ra1 = bm + r0 + 64;
    if (APERM) {
        ra0 = ((ra0 & 255) << 8) | (ra0 >> 8);
        ra1 = ((ra1 & 255) << 8) | (ra1 >> 8);
    }
    size_t sa0 = (size_t)ra0 * K, sa1 = (size_t)ra1 * K;
    size_t sb0 = (size_t)(bn + r0) * K, sb1 = (size_t)(bn + r0 + 64) * K;

    for (int k0 = 0; k0 < K; k0 += 32) {
        uint4 va0 = *(const uint4*)(A + sa0 + k0 + c0 * 8);
        uint4 va1 = *(const uint4*)(A + sa1 + k0 + c0 * 8);
        uint4 vb0 = *(const uint4*)(Bw + sb0 + k0 + c0 * 8);
        uint4 vb1 = *(const uint4*)(Bw + sb1 + k0 + c0 * 8);
        __syncthreads();
        *(uint4*)&As[r0 * 40 + c0 * 8] = va0;
        *(uint4*)&As[(r0 + 64) * 40 + c0 * 8] = va1;
        *(uint4*)&Bs[r0 * 40 + c0 * 8] = vb0;
        *(uint4*)&Bs[(r0 + 64) * 40 + c0 * 8] = vb1;
        __syncthreads();
        bf16x8 af[4], bfr[4];
#pragma unroll
        for (int f = 0; f < 4; f++) {
            af[f] = *(const bf16x8*)&As[(wm + f * 16 + lrow) * 40 + lchunk * 8];
            bfr[f] = *(const bf16x8*)&Bs[(wn + f * 16 + lrow) * 40 + lchunk * 8];
        }
#pragma unroll
        for (int fi = 0; fi < 4; fi++)
#pragma unroll
            for (int fj = 0; fj < 4; fj++)
                acc[fi][fj] = __builtin_amdgcn_mfma_f32_16x16x32_bf16(af[fi], bfr[fj], acc[fi][fj], 0, 0, 0);
    }
#pragma unroll
    for (int fi = 0; fi < 4; fi++) {
#pragma unroll
        for (int i = 0; i < 4; i++) {
            int gm = bm + wm + fi * 16 + lchunk * 4 + i;
            size_t crow = (size_t)gm * N;
#pragma unroll
            for (int fj = 0; fj < 4; fj++) {
                int gn = bn + wn + fj * 16 + lrow;
                float val = acc[fi][fj][i];
                if (bias) val += bias[gn];
                if (ACT == 1) val = 0.5f * val * (1.f + erff(val * 0.70710678118654752f));
                if (RES == 1) val += C[crow + gn];
                else if (RES == 2) val += R[crow + gn];
                if (OUTBF) Cb[crow + gn] = (bf16_t)val;
                else C[crow + gn] = val;
            }
        }
    }
}

// ---------------- colout + outer-sum + final z-LN fused ----------------
// C = obbf[perm(m)] @ wcout^T + coutb; z[m] += C + ab_i + ab_j; znp = LN(z) (z_norm params)
__global__ __launch_bounds__(256) void colout_fused_kernel(
        const bf16_t* __restrict__ A, const bf16_t* __restrict__ Bw,
        const float* __restrict__ bias, const float* __restrict__ ab,
        const float* __restrict__ zng, const float* __restrict__ znb,
        float* __restrict__ z, bf16_t* __restrict__ znp) {
    __shared__ __align__(16) char smem[128 * 129 * 4];
    bf16_t* As = (bf16_t*)smem;
    bf16_t* Bs = (bf16_t*)(smem + 10240);
    float* lnb = (float*)smem;
    int tid = threadIdx.x;
    int bm = blockIdx.x * 128;
    int lane = tid & 63, wvid = tid >> 6;
    int wm = (wvid >> 1) * 64, wn = (wvid & 1) * 64;
    int lrow = lane & 15, lchunk = lane >> 4;

    f32x4 acc[4][4];
#pragma unroll
    for (int i = 0; i < 4; i++)
#pragma unroll
        for (int j = 0; j < 4; j++) acc[i][j] = (f32x4){0.f, 0.f, 0.f, 0.f};

    int r0 = tid >> 2, c0 = tid & 3;
    int ra0 = bm + r0, ra1 = bm + r0 + 64;
    ra0 = ((ra0 & 255) << 8) | (ra0 >> 8);
    ra1 = ((ra1 & 255) << 8) | (ra1 >> 8);
    size_t sa0 = (size_t)ra0 * 128, sa1 = (size_t)ra1 * 128;
    size_t sb0 = (size_t)r0 * 128, sb1 = (size_t)(r0 + 64) * 128;

    for (int k0 = 0; k0 < 128; k0 += 32) {
        uint4 va0 = *(const uint4*)(A + sa0 + k0 + c0 * 8);
        uint4 va1 = *(const uint4*)(A + sa1 + k0 + c0 * 8);
        uint4 vb0 = *(const uint4*)(Bw + sb0 + k0 + c0 * 8);
        uint4 vb1 = *(const uint4*)(Bw + sb1 + k0 + c0 * 8);
        __syncthreads();
        *(uint4*)&As[r0 * 40 + c0 * 8] = va0;
        *(uint4*)&As[(r0 + 64) * 40 + c0 * 8] = va1;
        *(uint4*)&Bs[r0 * 40 + c0 * 8] = vb0;
        *(uint4*)&Bs[(r0 + 64) * 40 + c0 * 8] = vb1;
        __syncthreads();
        bf16x8 af[4], bfr[4];
#pragma unroll
        for (int f = 0; f < 4; f++) {
            af[f] = *(const bf16x8*)&As[(wm + f * 16 + lrow) * 40 + lchunk * 8];
            bfr[f] = *(const bf16x8*)&Bs[(wn + f * 16 + lrow) * 40 + lchunk * 8];
        }
#pragma unroll
        for (int fi = 0; fi < 4; fi++)
#pragma unroll
            for (int fj = 0; fj < 4; fj++)
                acc[fi][fj] = __builtin_amdgcn_mfma_f32_16x16x32_bf16(af[fi], bfr[fj], acc[fi][fj], 0, 0, 0);
    }
    __syncthreads();  // all As/Bs reads done before lnb aliases them
#pragma unroll
    for (int fi = 0; fi < 4; fi++) {
#pragma unroll
        for (int i = 0; i < 4; i++) {
            int lm = wm + fi * 16 + lchunk * 4 + i;
            int gm = bm + lm;
            int irow = gm >> 8, jcol = gm & 255;
            size_t crow = (size_t)gm * 128;
#pragma unroll
            for (int fj = 0; fj < 4; fj++) {
                int gn = wn + fj * 16 + lrow;
                float val = acc[fi][fj][i] + bias[gn] + z[crow + gn]
                          + ab[(size_t)irow * 256 + gn] + ab[(size_t)jcol * 256 + 128 + gn];
                z[crow + gn] = val;
                lnb[lm * 129 + gn] = val;
            }
        }
    }
    __syncthreads();
    {
        int r = tid >> 1, half = tid & 1;
        const float* rowp = &lnb[r * 129 + half * 64];
        float s = 0.f, s2 = 0.f;
#pragma unroll
        for (int q = 0; q < 64; q++) { float v = rowp[q]; s += v; s2 += v * v; }
        s += __shfl_xor(s, 1); s2 += __shfl_xor(s2, 1);
        float mean = s * 0.0078125f;
        float rstd = rsqrtf(s2 * 0.0078125f - mean * mean + 1e-5f);
        int gm = bm + r;
        bf16_t ob[64];
#pragma unroll
        for (int q = 0; q < 64; q++)
            ob[q] = (bf16_t)((rowp[q] - mean) * rstd * zng[half * 64 + q] + znb[half * 64 + q]);
        bf16_t* orow = znp + (size_t)gm * 128 + half * 64;
#pragma unroll
        for (int q = 0; q < 8; q++) *(uint4*)(orow + q * 8) = *(uint4*)&ob[q * 8];
    }
}

// ---------------- fused z feed-forward: z += gelu(znp@w1^T+b1)@w2^T + b2 ----------------
// 64 rows/block; weight chunks alternate in one shared buffer; h is wave-private LDS.
__global__ __launch_bounds__(256) void zff_fused_kernel(
        const bf16_t* __restrict__ znp, const bf16_t* __restrict__ w1,  // (512,128)
        const bf16_t* __restrict__ w2,                                  // (128,512)
        const float* __restrict__ b1, const float* __restrict__ b2,
        float* __restrict__ z) {
    __shared__ bf16_t Azn[64 * 136];
    __shared__ bf16_t Wbuf[128 * 136];
    __shared__ bf16_t Hbuf[4][16 * 136];
    int tid = threadIdx.x;
    int lane = tid & 63, wv = tid >> 6;
    int lrow = lane & 15, lchunk = lane >> 4;
    int r0 = blockIdx.x * 64;

    {
        int ar = tid >> 2;
        int ac = (tid & 3) * 32;
        const bf16_t* src = znp + (size_t)(r0 + ar) * 128 + ac;
#pragma unroll
        for (int q = 0; q < 4; q++)
            *(uint4*)&Azn[ar * 136 + ac + q * 8] = *(const uint4*)(src + q * 8);
    }

    f32x4 acc2[8];
#pragma unroll
    for (int j = 0; j < 8; j++) acc2[j] = (f32x4){0.f, 0.f, 0.f, 0.f};

    bf16_t* H = &Hbuf[wv][0];
    for (int nc = 0; nc < 4; nc++) {
        __syncthreads();  // Wbuf free (prev GEMM2 done); also covers Azn staging on nc=0
        {
            int wr = tid >> 1;
            int wc = (tid & 1) * 64;
            const bf16_t* src = w1 + (size_t)(nc * 128 + wr) * 128 + wc;
#pragma unroll
            for (int q = 0; q < 8; q++)
                *(uint4*)&Wbuf[wr * 136 + wc + q * 8] = *(const uint4*)(src + q * 8);
        }
        __syncthreads();
        // GEMM1: h(16 rows of this wave x 128) = Azn @ w1c^T
        f32x4 acc1[8];
#pragma unroll
        for (int j = 0; j < 8; j++) acc1[j] = (f32x4){0.f, 0.f, 0.f, 0.f};
#pragma unroll
        for (int ki = 0; ki < 4; ki++) {
            bf16x8 a = *(const bf16x8*)&Azn[(wv * 16 + lrow) * 136 + ki * 32 + lchunk * 8];
#pragma unroll
            for (int fj = 0; fj < 8; fj++) {
                bf16x8 b = *(const bf16x8*)&Wbuf[(fj * 16 + lrow) * 136 + ki * 32 + lchunk * 8];
                acc1[fj] = __builtin_amdgcn_mfma_f32_16x16x32_bf16(a, b, acc1[fj], 0, 0, 0);
            }
        }
        // gelu -> Hbuf (wave-private; no barrier needed)
#pragma unroll
        for (int fj = 0; fj < 8; fj++) {
            int col = fj * 16 + lrow;
            float bb = b1[nc * 128 + col];
#pragma unroll
            for (int ii = 0; ii < 4; ii++) {
                float v = acc1[fj][ii] + bb;
                v = 0.5f * v * (1.f + erff(v * 0.70710678118654752f));
                H[(lchunk * 4 + ii) * 136 + col] = (bf16_t)v;
            }
        }
        __syncthreads();  // all waves done with w1c before restaging
        {
            int wr = tid >> 1;
            int wc = (tid & 1) * 64;
            const bf16_t* src = w2 + (size_t)wr * 512 + nc * 128 + wc;
#pragma unroll
            for (int q = 0; q < 8; q++)
                *(uint4*)&Wbuf[wr * 136 + wc + q * 8] = *(const uint4*)(src + q * 8);
        }
        __syncthreads();
        // GEMM2: acc2 += H @ w2c^T
#pragma unroll
        for (int ki = 0; ki < 4; ki++) {
            bf16x8 a = *(const bf16x8*)&H[lrow * 136 + ki * 32 + lchunk * 8];
#pragma unroll
            for (int fj = 0; fj < 8; fj++) {
                bf16x8 b = *(const bf16x8*)&Wbuf[(fj * 16 + lrow) * 136 + ki * 32 + lchunk * 8];
                acc2[fj] = __builtin_amdgcn_mfma_f32_16x16x32_bf16(a, b, acc2[fj], 0, 0, 0);
            }
        }
    }
#pragma unroll
    for (int fj = 0; fj < 8; fj++) {
        int col = fj * 16 + lrow;
        float bb = b2[col];
#pragma unroll
        for (int ii = 0; ii < 4; ii++) {
            int grow = r0 + wv * 16 + lchunk * 4 + ii;
            size_t idx = (size_t)grow * 128 + col;
            z[idx] += acc2[fj][ii] + bb;
        }
    }
}

// ---------------- one-shot weight prep ----------------
struct PrepArgs {
    const float *wq, *wk, *wv, *wo, *sffw1, *sffw2, *szi, *szj, *zffw1, *zffw2;
    const float *rinw, *cinw, *routw, *coutw, *bq, *bk, *bv;
    bf16_t *wqkv, *wwo, *wsf1, *wsf2, *wszij, *wzf1, *wzf2;
    bf16_t *wrin, *wcin, *wrout, *wcout;
    float* biasqkv;
};
__device__ inline void dev_trans(const float* in, bf16_t* out, int i, int N, int K) {
    int k = i / N, n = i % N;
    out[(size_t)n * K + k] = (bf16_t)in[i];
}
__global__ void prep_kernel(PrepArgs a) {
    int i = blockIdx.x * 256 + threadIdx.x;
    if (i < 147456) { dev_trans(a.wq, a.wqkv, i, 384, 384); return; }
    i -= 147456;
    if (i < 147456) { dev_trans(a.wk, a.wqkv + 384 * 384, i, 384, 384); return; }
    i -= 147456;
    if (i < 147456) { dev_trans(a.wv, a.wqkv + 768 * 384, i, 384, 384); return; }
    i -= 147456;
    if (i < 147456) { dev_trans(a.wo, a.wwo, i, 384, 384); return; }
    i -= 147456;
    if (i < 589824) { dev_trans(a.sffw1, a.wsf1, i, 1536, 384); return; }
    i -= 589824;
    if (i < 589824) { dev_trans(a.sffw2, a.wsf2, i, 384, 1536); return; }
    i -= 589824;
    if (i < 49152) { dev_trans(a.szi, a.wszij, i, 128, 384); return; }
    i -= 49152;
    if (i < 49152) { dev_trans(a.szj, a.wszij + 128 * 384, i, 128, 384); return; }
    i -= 49152;
    if (i < 65536) { dev_trans(a.zffw1, a.wzf1, i, 512, 128); return; }
    i -= 65536;
    if (i < 65536) { dev_trans(a.zffw2, a.wzf2, i, 128, 512); return; }
    i -= 65536;
    if (i < 49152) { a.wrin[i] = (bf16_t)a.rinw[i]; return; }
    i -= 49152;
    if (i < 49152) { a.wcin[i] = (bf16_t)a.cinw[i]; return; }
    i -= 49152;
    if (i < 16384) { a.wrout[i] = (bf16_t)a.routw[i]; return; }
    i -= 16384;
    if (i < 16384) { a.wcout[i] = (bf16_t)a.coutw[i]; return; }
    i -= 16384;
    if (i < 384) { a.biasqkv[i] = a.bq[i]; return; }
    i -= 384;
    if (i < 384) { a.biasqkv[384 + i] = a.bk[i]; return; }
    i -= 384;
    if (i < 384) { a.biasqkv[768 + i] = a.bv[i]; return; }
}

extern "C" void kernel_launch(void* const* d_in, const int* in_sizes, int n_in,
                              void* d_out, int out_size, void* d_ws, size_t ws_size,
                              hipStream_t stream) {
    const float* s_in = (const float*)d_in[0];
    const float* z_in = (const float*)d_in[1];
    const float* sng = (const float*)d_in[3];
    const float* snb = (const float*)d_in[4];
    const float* zng = (const float*)d_in[5];
    const float* znb = (const float*)d_in[6];
    const float* wq = (const float*)d_in[7];
    const float* bq = (const float*)d_in[8];
    const float* wk = (const float*)d_in[9];
    const float* bk = (const float*)d_in[10];
    const float* wv = (const float*)d_in[11];
    const float* bv = (const float*)d_in[12];
    const float* wzb = (const float*)d_in[13];
    const float* bzb = (const float*)d_in[14];
    const float* wo = (const float*)d_in[15];
    const float* bo = (const float*)d_in[16];
    const float* sffw1 = (const float*)d_in[17];
    const float* sffb1 = (const float*)d_in[18];
    const float* sffw2 = (const float*)d_in[19];
    const float* sffb2 = (const float*)d_in[20];
    const float* pzg = (const float*)d_in[21];
    const float* pzb = (const float*)d_in[22];
    const float* rinw = (const float*)d_in[23];
    const float* rinb = (const float*)d_in[24];
    const float* routw = (const float*)d_in[25];
    const float* routb = (const float*)d_in[26];
    const float* cinw = (const float*)d_in[27];
    const float* cinb = (const float*)d_in[28];
    const float* coutw = (const float*)d_in[29];
    const float* coutb = (const float*)d_in[30];
    const float* sziw = (const float*)d_in[31];
    const float* szjw = (const float*)d_in[32];
    const float* zffw1 = (const float*)d_in[33];
    const float* zffb1 = (const float*)d_in[34];
    const float* zffw2 = (const float*)d_in[35];
    const float* zffb2 = (const float*)d_in[36];

    float* ws = (float*)d_ws;
    bf16_t* qkvbf = (bf16_t*)ws;                   // 65536x384 bf16
    float* obregion = ws + 25165824;               // 4,194,304 floats region
    bf16_t* obbf = (bf16_t*)obregion;              // 65536x128 bf16 (z-track stage)
    bf16_t* znpbf = (bf16_t*)(ws + 29360128);      // 65536x128 bf16
    // s-track transients overlaid in obregion (dead before pattn writes obbf)
    bf16_t* snbf = (bf16_t*)obregion;
    float* qkv_s = obregion + 49152;
    float* biasb = obregion + 344064;
    bf16_t* osbf = (bf16_t*)(obregion + 868352);
    float* s1 = obregion + 917504;
    bf16_t* sn2bf = (bf16_t*)(obregion + 1015808);
    bf16_t* hsbf = (bf16_t*)(obregion + 1064960);
    // persistent weight region
    bf16_t* wrin = (bf16_t*)(ws + 33554432);
    bf16_t* wcin = (bf16_t*)(ws + 33579008);
    bf16_t* wrout = (bf16_t*)(ws + 33603584);
    bf16_t* wcout = (bf16_t*)(ws + 33611776);
    bf16_t* wzf1 = (bf16_t*)(ws + 33619968);
    bf16_t* wzf2 = (bf16_t*)(ws + 33652736);
    bf16_t* wqkv = (bf16_t*)(ws + 33685504);
    bf16_t* wwo = (bf16_t*)(ws + 33906688);
    bf16_t* wsf1 = (bf16_t*)(ws + 33980416);
    bf16_t* wsf2 = (bf16_t*)(ws + 34275328);
    bf16_t* wszij = (bf16_t*)(ws + 34570240);
    float* biasqkv = ws + 34619392;
    bf16_t* sn3bf = (bf16_t*)(ws + 34620544);
    float* ab = ws + 34669696;

    float* sout = (float*)d_out;
    float* zout = sout + 98304;

    dim3 b256(256);

    // --- all weight prep in one dispatch ---
    PrepArgs pa;
    pa.wq = wq; pa.wk = wk; pa.wv = wv; pa.wo = wo;
    pa.sffw1 = sffw1; pa.sffw2 = sffw2; pa.szi = sziw; pa.szj = szjw;
    pa.zffw1 = zffw1; pa.zffw2 = zffw2;
    pa.rinw = rinw; pa.cinw = cinw; pa.routw = routw; pa.coutw = coutw;
    pa.bq = bq; pa.bk = bk; pa.bv = bv;
    pa.wqkv = wqkv; pa.wwo = wwo; pa.wsf1 = wsf1; pa.wsf2 = wsf2; pa.wszij = wszij;
    pa.wzf1 = wzf1; pa.wzf2 = wzf2;
    pa.wrin = wrin; pa.wcin = wcin; pa.wrout = wrout; pa.wcout = wcout;
    pa.biasqkv = biasqkv;
    prep_kernel<<<dim3(8329), b256, 0, stream>>>(pa);

    // --- fused z LN: znp (bf16) + pair bias, one pass over z ---
    zlnbias_kernel<<<dim3(2048), b256, 0, stream>>>(z_in, zng, znb, pzg, pzb, wzb, bzb, biasb, znpbf);

    // --- s attention ---
    ln_kernel<bf16_t><<<dim3(LL), dim3(CSD), 0, stream>>>(s_in, sng, snb, snbf, CSD);
    sgemm_kernel<0, 0, 0><<<dim3(18, 4), b256, 0, stream>>>(snbf, wqkv, biasqkv, nullptr, qkv_s, nullptr, 256, 1152, 384);
    sattn_kernel<<<dim3(LL, HNUM), b256, 0, stream>>>(qkv_s, biasb, osbf);
    sgemm_kernel<2, 0, 0><<<dim3(6, 4), b256, 0, stream>>>(osbf, wwo, bo, s_in, s1, nullptr, 256, 384, 384);
    // --- s feedforward ---
    ln_kernel<bf16_t><<<dim3(LL), dim3(CSD), 0, stream>>>(s1, sng, snb, sn2bf, CSD);
    sgemm_kernel<0, 1, 1><<<dim3(24, 4), b256, 0, stream>>>(sn2bf, wsf1, sffb1, nullptr, nullptr, hsbf, 256, 1536, 384);
    sgemm_kernel<2, 0, 0><<<dim3(6, 4), b256, 0, stream>>>(hsbf, wsf2, sffb2, s1, sout, nullptr, 256, 384, 1536);
    // --- outer-sum inputs ---
    ln_kernel<bf16_t><<<dim3(LL), dim3(CSD), 0, stream>>>(sout, sng, snb, sn3bf, CSD);
    sgemm_kernel<0, 0, 0><<<dim3(4, 4), b256, 0, stream>>>(sn3bf, wszij, nullptr, nullptr, ab, nullptr, 256, 256, 384);
    // --- row attention ---
    mgemm_kernel<0, 0, 0, 1><<<dim3(3, 512), b256, 0, stream>>>(znpbf, wrin, rinb, nullptr, nullptr, qkvbf, 65536, 384, CZD);
    pattn_mfma_kernel<<<dim3(256, HNUM), b256, 0, stream>>>(qkvbf, obbf);
    mgemm_kernel<0, 2, 0, 0><<<dim3(1, 512), b256, 0, stream>>>(obbf, wrout, routb, z_in, zout, nullptr, 65536, CZD, CZD);
    // --- col attention ---
    mgemm_kernel<1, 0, 0, 1><<<dim3(3, 512), b256, 0, stream>>>(znpbf, wcin, cinb, nullptr, nullptr, qkvbf, 65536, 384, CZD);
    pattn_mfma_kernel<<<dim3(256, HNUM), b256, 0, stream>>>(qkvbf, obbf);
    // --- col out-proj + outer sum + final z-LN (one kernel) ---
    colout_fused_kernel<<<dim3(512), b256, 0, stream>>>(obbf, wcout, coutb, ab, zng, znb, zout, znpbf);
    // --- fused z feedforward ---
    zff_fused_kernel<<<dim3(1024), b256, 0, stream>>>(znpbf, wzf1, wzf2, zffb1, zffb2, zout);
}